// Round 12
// baseline (40108.914 us; speedup 1.0000x reference)
//
#include <hip/hip_runtime.h>
#include <stdint.h>
#include <math.h>

#define TT 256
#define VOCAB 32000
#define LN_EPS 1e-5
#define NBLK 192

typedef __attribute__((ext_vector_type(8))) short bf16x8;
typedef __attribute__((ext_vector_type(4))) float f32x4;

__device__ __forceinline__ float bf2f(short s) {
  return __uint_as_float(((uint32_t)(uint16_t)s) << 16);
}
__device__ __forceinline__ short f2bf(float f) {
  uint32_t u = __float_as_uint(f);
  u += 0x7fffu + ((u >> 16) & 1u);
  return (short)(u >> 16);
}
__device__ __forceinline__ f32x4 mfma16(bf16x8 a, bf16x8 b, f32x4 c) {
  return __builtin_amdgcn_mfma_f32_16x16x32_bf16(a, b, c, 0, 0, 0);
}

// ---------------- gi0 = embd[input] @ Wih0^T + bih0, f64, fully parallel ----------------
__global__ void k_gi0(const int* __restrict__ input, const float* __restrict__ embd,
                      const float* __restrict__ Wih0, const float* __restrict__ bih0,
                      double* __restrict__ gi0) {
  const int t = blockIdx.x >> 4;
  const int cg = blockIdx.x & 15;
  const int tid = threadIdx.x;
  __shared__ float xs[16][512];
  for (int idx = tid; idx < 16 * 512; idx += 256) {
    const int r = idx >> 9, j = idx & 511;
    const int tok = input[r * TT + t];
    xs[r][j] = embd[(size_t)tok * 512 + j];
  }
  __syncthreads();
  const int row = tid >> 4, ct = tid & 15;
  for (int i = 0; i < 12; ++i) {
    const int c = cg * 192 + ct + 16 * i;
    const float4* wp = (const float4*)(Wih0 + (size_t)c * 512);
    const float4* xp = (const float4*)&xs[row][0];
    double acc = 0.0;
#pragma unroll 8
    for (int j4 = 0; j4 < 128; ++j4) {
      const float4 w = wp[j4];
      const float4 x = xp[j4];
      acc = fma((double)x.x, (double)w.x, acc);
      acc = fma((double)x.y, (double)w.y, acc);
      acc = fma((double)x.z, (double)w.z, acc);
      acc = fma((double)x.w, (double)w.w, acc);
    }
    gi0[((size_t)t * 16 + row) * 3072 + c] = acc + (double)bih0[c];
  }
}

// ---------------- persistent recurrence: REGISTER-RESIDENT WEIGHTS ----------------
// Round 11 evidence: FETCH 5.9GB = 36MB f32 weights re-fetched from HBM EVERY
// phase (36MB > 32MB L2 -> thrash, ~300GB/s). Fix: each block's 192KB weight
// slice lives in VGPRs (96 f64/thread at 512 threads = 192 VGPR), loaded once.
// Per phase: stage LN-normalized f64 activations to a_lds[16][1024] (contiguous
// 16B/lane, conflict-free), dot waves read b128 (contiguous 1KB/wave) amortized
// over 6 register weight columns, f64 FMA, shfl-reduce, lane-parallel gates.
struct SP {
  const float *Whh0, *bhh0, *ln0w, *ln0b;
  const float *Wih1, *Whh1, *bih1, *bhh1, *ln1w, *ln1b;
  const double* gi0;
  double *h0ring, *h1ring;  // [2][16][1024] f64 raw hidden states
  float* h1hist;            // [256*16][1024] f32 raw h1 history
  int* bar;
};

// stage one row: lane l owns k in {l*2 + 128*jj + u}. LN stats via 6-step shfl.
__device__ __forceinline__ void stage2(const double* __restrict__ hrow,
                                       const float* __restrict__ lnw,
                                       const float* __restrict__ lnb,
                                       const int l, double* __restrict__ aout,
                                       double& m_out, double& rs_out) {
  double a[16];
  double s = 0.0, q = 0.0;
#pragma unroll
  for (int jj = 0; jj < 8; ++jj) {
    const double2 x = *(const double2*)(hrow + jj * 128 + l * 2);
    a[jj*2] = x.x; a[jj*2+1] = x.y;
    s += x.x + x.y; q += x.x*x.x + x.y*x.y;
  }
#pragma unroll
  for (int mk = 1; mk <= 32; mk <<= 1) { s += __shfl_xor(s, mk); q += __shfl_xor(q, mk); }
  const double m = s * (1.0 / 1024.0);
  const double rs = 1.0 / sqrt(q * (1.0 / 1024.0) - m * m + LN_EPS);
#pragma unroll
  for (int jj = 0; jj < 8; ++jj) {
    const float2 lw = *(const float2*)(lnw + jj * 128 + l * 2);
    const float2 lb = *(const float2*)(lnb + jj * 128 + l * 2);
    double2 o;
    o.x = (a[jj*2]   - m) * rs * (double)lw.x + (double)lb.x;
    o.y = (a[jj*2+1] - m) * rs * (double)lw.y + (double)lb.y;
    *(double2*)(aout + jj * 128 + l * 2) = o;
  }
  m_out = m; rs_out = rs;
}

__launch_bounds__(512, 1)
__global__ void k_recur(SP A) {
  __shared__ double a_lds[16][1024];  // 128KB normalized activations
  __shared__ double sPre[48][16];     // gate dot sums [slot][row]
  __shared__ double sM[16], sR[16];
  const int tid = threadIdx.x;
  const int w = tid >> 6;  // wave 0..7
  const int l = tid & 63;
  const int bid = blockIdx.x;
  const int col0 = (bid < 64) ? bid * 16 : (bid - 64) * 8;

  // ---- one-time: weight slice -> registers (f64). L0: 6 col-gates/wave of
  // Whh0 (cg = w*6+j, col=col0+cg/3, gate=cg%3). L1: 3 of Wih1 + 3 of Whh1
  // (cg = w*3+j). Lane l holds k in {l*2 + 128*jj + u}. All static-indexed.
  double wreg[6][16];
  if (bid < 64) {
#pragma unroll
    for (int j = 0; j < 6; ++j) {
      const int cg = w * 6 + j;
      const size_t wrow = (size_t)((cg % 3) * 1024 + col0 + cg / 3) * 1024;
#pragma unroll
      for (int jj = 0; jj < 8; ++jj) {
        const float2 v = *(const float2*)(A.Whh0 + wrow + jj * 128 + l * 2);
        wreg[j][jj*2] = (double)v.x; wreg[j][jj*2+1] = (double)v.y;
      }
    }
  } else {
#pragma unroll
    for (int j = 0; j < 3; ++j) {
      const int cg = w * 3 + j;
      const size_t wrow = (size_t)((cg % 3) * 1024 + col0 + cg / 3) * 1024;
#pragma unroll
      for (int jj = 0; jj < 8; ++jj) {
        const float2 v = *(const float2*)(A.Wih1 + wrow + jj * 128 + l * 2);
        wreg[j][jj*2] = (double)v.x; wreg[j][jj*2+1] = (double)v.y;
        const float2 u = *(const float2*)(A.Whh1 + wrow + jj * 128 + l * 2);
        wreg[3+j][jj*2] = (double)u.x; wreg[3+j][jj*2+1] = (double)u.y;
      }
    }
  }

  for (int p = 0; p <= TT; ++p) {
    if (bid < 64) {
      // ================= layer0, t = p =================
      const int t = p;
      if (t < TT) {
        if (t > 0) {
          double mm, rr;
          stage2(A.h0ring + (size_t)((t - 1) & 1) * 16384 + w * 1024,
                 A.ln0w, A.ln0b, l, &a_lds[w][0], mm, rr);
          if (l == 0) { sM[w] = mm; sR[w] = rr; }
          stage2(A.h0ring + (size_t)((t - 1) & 1) * 16384 + (w + 8) * 1024,
                 A.ln0w, A.ln0b, l, &a_lds[w + 8][0], mm, rr);
          if (l == 0) { sM[w + 8] = mm; sR[w + 8] = rr; }
          __syncthreads();
          for (int r = 0; r < 16; ++r) {
            double c0=0,c1=0,c2=0,c3=0,c4=0,c5=0;
#pragma unroll
            for (int jj = 0; jj < 8; ++jj) {
              const double2 av = *(const double2*)(&a_lds[r][jj*128 + l*2]);
              c0 = fma(wreg[0][jj*2],av.x,c0); c0 = fma(wreg[0][jj*2+1],av.y,c0);
              c1 = fma(wreg[1][jj*2],av.x,c1); c1 = fma(wreg[1][jj*2+1],av.y,c1);
              c2 = fma(wreg[2][jj*2],av.x,c2); c2 = fma(wreg[2][jj*2+1],av.y,c2);
              c3 = fma(wreg[3][jj*2],av.x,c3); c3 = fma(wreg[3][jj*2+1],av.y,c3);
              c4 = fma(wreg[4][jj*2],av.x,c4); c4 = fma(wreg[4][jj*2+1],av.y,c4);
              c5 = fma(wreg[5][jj*2],av.x,c5); c5 = fma(wreg[5][jj*2+1],av.y,c5);
            }
#pragma unroll
            for (int mk = 1; mk <= 32; mk <<= 1) {
              c0 += __shfl_xor(c0, mk); c1 += __shfl_xor(c1, mk); c2 += __shfl_xor(c2, mk);
              c3 += __shfl_xor(c3, mk); c4 += __shfl_xor(c4, mk); c5 += __shfl_xor(c5, mk);
            }
            if (l == 0) {
              sPre[w*6+0][r] = c0; sPre[w*6+1][r] = c1; sPre[w*6+2][r] = c2;
              sPre[w*6+3][r] = c3; sPre[w*6+4][r] = c4; sPre[w*6+5][r] = c5;
            }
          }
        } else {
          for (int i = tid; i < 768; i += 512) ((double*)sPre)[i] = 0.0;
        }
        __syncthreads();
        if (tid < 256) {
          const int r2 = tid >> 4, ci = tid & 15;
          const int c = col0 + ci;
          const double ghr = sPre[ci*3+0][r2] + (double)A.bhh0[c];
          const double ghz = sPre[ci*3+1][r2] + (double)A.bhh0[c + 1024];
          const double ghn = sPre[ci*3+2][r2] + (double)A.bhh0[c + 2048];
          const double* gp = A.gi0 + ((size_t)t * 16 + r2) * 3072 + c;
          const double gir = gp[0], giz = gp[1024], gin = gp[2048];
          const double rg = 1.0 / (1.0 + exp(-(gir + ghr)));
          const double zg = 1.0 / (1.0 + exp(-(giz + ghz)));
          const double ng = tanh(gin + rg * ghn);
          double hprev = 0.0;
          if (t > 0) {
            const double praw = A.h0ring[(size_t)((t - 1) & 1) * 16384 + r2 * 1024 + c];
            hprev = (praw - sM[r2]) * sR[r2] * (double)A.ln0w[c] + (double)A.ln0b[c];
          }
          A.h0ring[(size_t)(t & 1) * 16384 + r2 * 1024 + c] = (1.0 - zg) * ng + zg * hprev;
        }
      }
    } else {
      // ================= layer1, t = p-1, two-pass =================
      const int t = p - 1;
      if (t >= 0 && t < TT) {
        // ---- pass A: a0 = LN0(h0(t)), Wih1 dots -> slots 0..23 ----
        {
          double mm, rr;
          stage2(A.h0ring + (size_t)(t & 1) * 16384 + w * 1024,
                 A.ln0w, A.ln0b, l, &a_lds[w][0], mm, rr);
          stage2(A.h0ring + (size_t)(t & 1) * 16384 + (w + 8) * 1024,
                 A.ln0w, A.ln0b, l, &a_lds[w + 8][0], mm, rr);
        }
        __syncthreads();
        for (int r = 0; r < 16; ++r) {
          double c0=0,c1=0,c2=0;
#pragma unroll
          for (int jj = 0; jj < 8; ++jj) {
            const double2 av = *(const double2*)(&a_lds[r][jj*128 + l*2]);
            c0 = fma(wreg[0][jj*2],av.x,c0); c0 = fma(wreg[0][jj*2+1],av.y,c0);
            c1 = fma(wreg[1][jj*2],av.x,c1); c1 = fma(wreg[1][jj*2+1],av.y,c1);
            c2 = fma(wreg[2][jj*2],av.x,c2); c2 = fma(wreg[2][jj*2+1],av.y,c2);
          }
#pragma unroll
          for (int mk = 1; mk <= 32; mk <<= 1) {
            c0 += __shfl_xor(c0, mk); c1 += __shfl_xor(c1, mk); c2 += __shfl_xor(c2, mk);
          }
          if (l == 0) {
            sPre[w*3+0][r] = c0; sPre[w*3+1][r] = c1; sPre[w*3+2][r] = c2;
          }
        }
        __syncthreads();  // dotsA done; a_lds reusable
        // ---- pass B: a1 = LN1(h1(t-1)), Whh1 dots -> slots 24..47 ----
        if (t > 0) {
          double mm, rr;
          stage2(A.h1ring + (size_t)((t - 1) & 1) * 16384 + w * 1024,
                 A.ln1w, A.ln1b, l, &a_lds[w][0], mm, rr);
          if (l == 0) { sM[w] = mm; sR[w] = rr; }
          stage2(A.h1ring + (size_t)((t - 1) & 1) * 16384 + (w + 8) * 1024,
                 A.ln1w, A.ln1b, l, &a_lds[w + 8][0], mm, rr);
          if (l == 0) { sM[w + 8] = mm; sR[w + 8] = rr; }
          __syncthreads();
          for (int r = 0; r < 16; ++r) {
            double c0=0,c1=0,c2=0;
#pragma unroll
            for (int jj = 0; jj < 8; ++jj) {
              const double2 av = *(const double2*)(&a_lds[r][jj*128 + l*2]);
              c0 = fma(wreg[3][jj*2],av.x,c0); c0 = fma(wreg[3][jj*2+1],av.y,c0);
              c1 = fma(wreg[4][jj*2],av.x,c1); c1 = fma(wreg[4][jj*2+1],av.y,c1);
              c2 = fma(wreg[5][jj*2],av.x,c2); c2 = fma(wreg[5][jj*2+1],av.y,c2);
            }
#pragma unroll
            for (int mk = 1; mk <= 32; mk <<= 1) {
              c0 += __shfl_xor(c0, mk); c1 += __shfl_xor(c1, mk); c2 += __shfl_xor(c2, mk);
            }
            if (l == 0) {
              sPre[24+w*3+0][r] = c0; sPre[24+w*3+1][r] = c1; sPre[24+w*3+2][r] = c2;
            }
          }
        } else {
          for (int i = tid; i < 384; i += 512) ((double*)sPre)[384 + i] = 0.0;
        }
        __syncthreads();
        if (tid < 128) {
          const int r2 = tid >> 3, ci = tid & 7;
          const int c = col0 + ci;
          const double gir = sPre[ci*3+0][r2] + (double)A.bih1[c];
          const double giz = sPre[ci*3+1][r2] + (double)A.bih1[c + 1024];
          const double gin = sPre[ci*3+2][r2] + (double)A.bih1[c + 2048];
          const double ghr = sPre[24+ci*3+0][r2] + (double)A.bhh1[c];
          const double ghz = sPre[24+ci*3+1][r2] + (double)A.bhh1[c + 1024];
          const double ghn = sPre[24+ci*3+2][r2] + (double)A.bhh1[c + 2048];
          const double rg = 1.0 / (1.0 + exp(-(gir + ghr)));
          const double zg = 1.0 / (1.0 + exp(-(giz + ghz)));
          const double ng = tanh(gin + rg * ghn);
          double hprev = 0.0;
          if (t > 0) {
            const double praw = A.h1ring[(size_t)((t - 1) & 1) * 16384 + r2 * 1024 + c];
            hprev = (praw - sM[r2]) * sR[r2] * (double)A.ln1w[c] + (double)A.ln1b[c];
          }
          const double hnew = (1.0 - zg) * ng + zg * hprev;
          A.h1ring[(size_t)(t & 1) * 16384 + r2 * 1024 + c] = hnew;
          A.h1hist[((size_t)t * 16 + r2) * 1024 + c] = (float)hnew;
        }
      }
    }

    // ---------- grid barrier ----------
    __syncthreads();
    if (tid == 0) {
      __threadfence();
      __hip_atomic_fetch_add(A.bar, 1, __ATOMIC_ACQ_REL, __HIP_MEMORY_SCOPE_AGENT);
      const int target = NBLK * (p + 1);
      while (__hip_atomic_load(A.bar, __ATOMIC_ACQUIRE, __HIP_MEMORY_SCOPE_AGENT) < target) {
        __builtin_amdgcn_s_sleep(2);
      }
      __threadfence();
    }
    __syncthreads();
  }
}

// ---------------- batched head pre-proj (byte-identical to rounds 7-11) ----------------
__launch_bounds__(512, 2)
__global__ void k_headpre(const float* __restrict__ h1hist, const float* __restrict__ ln1w,
                          const float* __restrict__ ln1b, const float* __restrict__ W1,
                          const float* __restrict__ b1, short* __restrict__ araw) {
  const int tid = threadIdx.x;
  const int row = tid >> 5, ks = tid & 31;
  const size_t m = (size_t)blockIdx.x * 16 + row;
  const float* hp = h1hist + m * 1024;
  float a[32];
  float s = 0.f, q = 0.f;
#pragma unroll
  for (int g = 0; g < 8; ++g) {
    const float4 v = *(const float4*)(hp + g * 128 + ks * 4);
    a[g*4+0] = v.x; a[g*4+1] = v.y; a[g*4+2] = v.z; a[g*4+3] = v.w;
    s += v.x + v.y + v.z + v.w;
    q += v.x * v.x + v.y * v.y + v.z * v.z + v.w * v.w;
  }
#pragma unroll
  for (int mk = 1; mk <= 16; mk <<= 1) { s += __shfl_xor(s, mk); q += __shfl_xor(q, mk); }
  const float mn = s * (1.f / 1024.f);
  const float rs = rsqrtf(q * (1.f / 1024.f) - mn * mn + 1e-5f);
#pragma unroll
  for (int g = 0; g < 8; ++g) {
    const float4 lw = *(const float4*)(ln1w + g * 128 + ks * 4);
    const float4 lb = *(const float4*)(ln1b + g * 128 + ks * 4);
    a[g*4+0] = (a[g*4+0] - mn) * rs * lw.x + lb.x;
    a[g*4+1] = (a[g*4+1] - mn) * rs * lw.y + lb.y;
    a[g*4+2] = (a[g*4+2] - mn) * rs * lw.z + lb.z;
    a[g*4+3] = (a[g*4+3] - mn) * rs * lw.w + lb.w;
  }
  for (int c = 0; c < 1024; ++c) {
    const float4* wp = (const float4*)(W1 + (size_t)c * 1024);
    float acc = 0.f;
#pragma unroll
    for (int g = 0; g < 8; ++g) {
      const float4 w = wp[g * 32 + ks];
      acc = fmaf(a[g*4+0], w.x, acc); acc = fmaf(a[g*4+1], w.y, acc);
      acc = fmaf(a[g*4+2], w.z, acc); acc = fmaf(a[g*4+3], w.w, acc);
    }
#pragma unroll
    for (int mk = 1; mk <= 16; mk <<= 1) acc += __shfl_xor(acc, mk);
    if (ks == 0) {
      const float y = acc + b1[c];
      araw[m * 1024 + c] = f2bf(y > 0.f ? y : 0.01f * y);
    }
  }
}

// ---------------- head GEMM (byte-identical to rounds 6-11) ----------------
__global__ void k_head(const short* __restrict__ araw, const float* __restrict__ W2,
                       const float* __restrict__ ln2w, const float* __restrict__ ln2b,
                       const float* __restrict__ b2, float* __restrict__ C) {
  __shared__ __align__(16) short As[128 * 64];
  __shared__ __align__(16) short Bs[128 * 64];
  __shared__ float rowm[128], rowr[128];
  __shared__ float lnw_s[1024], lnb_s[1024];
  __shared__ float ps[256], pq[256];
  const int tid = threadIdx.x;
  const long brow = (long)blockIdx.y * 128;
  const long bcol = (long)blockIdx.x * 128;

  for (int i = tid; i < 1024; i += 256) { lnw_s[i] = ln2w[i]; lnb_s[i] = ln2b[i]; }
  {
    const int r2 = tid >> 1, hf = tid & 1;
    const short* ap = araw + (brow + r2) * 1024 + hf * 512;
    float s = 0.f, q = 0.f;
    for (int j = 0; j < 512; j += 8) {
      const bf16x8 v = *(const bf16x8*)(ap + j);
#pragma unroll
      for (int e = 0; e < 8; ++e) { const float x = bf2f(v[e]); s += x; q += x * x; }
    }
    ps[tid] = s; pq[tid] = q;
  }
  __syncthreads();
  if (tid < 128) {
    const float s = ps[2 * tid] + ps[2 * tid + 1];
    const float q = pq[2 * tid] + pq[2 * tid + 1];
    const float m = s * (1.f / 1024.f);
    rowm[tid] = m;
    rowr[tid] = rsqrtf(q * (1.f / 1024.f) - m * m + 1e-5f);
  }
  __syncthreads();

  const int l = tid & 63;
  const int w = tid >> 6;
  const int wm = w >> 1, wn = w & 1;
  const int lane15 = l & 15, lgrp = l >> 4;
  f32x4 zero4 = {0.f, 0.f, 0.f, 0.f};
  f32x4 acc[4][4];
#pragma unroll
  for (int ri = 0; ri < 4; ++ri)
#pragma unroll
    for (int ci = 0; ci < 4; ++ci) acc[ri][ci] = zero4;

  for (int k0 = 0; k0 < 1024; k0 += 64) {
    __syncthreads();
#pragma unroll
    for (int i = 0; i < 4; ++i) {
      const int c = tid + i * 256;
      const int r = c >> 3, cc = c & 7;
      const int k = k0 + cc * 8;
      {
        const bf16x8 v = *(const bf16x8*)(araw + (brow + r) * 1024 + k);
        const float mm = rowm[r], rr = rowr[r];
        bf16x8 o;
#pragma unroll
        for (int e = 0; e < 8; ++e)
          o[e] = f2bf((bf2f(v[e]) - mm) * rr * lnw_s[k + e] + lnb_s[k + e]);
        *(bf16x8*)&As[r * 64 + cc * 8] = o;
      }
      {
        const float4* bp = (const float4*)(W2 + (bcol + r) * 1024 + k);
        const float4 v0 = bp[0], v1 = bp[1];
        bf16x8 o;
        o[0] = f2bf(v0.x); o[1] = f2bf(v0.y); o[2] = f2bf(v0.z); o[3] = f2bf(v0.w);
        o[4] = f2bf(v1.x); o[5] = f2bf(v1.y); o[6] = f2bf(v1.z); o[7] = f2bf(v1.w);
        *(bf16x8*)&Bs[r * 64 + cc * 8] = o;
      }
    }
    __syncthreads();
#pragma unroll
    for (int kk = 0; kk < 2; ++kk) {
      const int ko = kk * 32 + lgrp * 8;
      bf16x8 av[4], bv[4];
#pragma unroll
      for (int ri = 0; ri < 4; ++ri) av[ri] = *(const bf16x8*)&As[(wm * 64 + ri * 16 + lane15) * 64 + ko];
#pragma unroll
      for (int ci = 0; ci < 4; ++ci) bv[ci] = *(const bf16x8*)&Bs[(wn * 64 + ci * 16 + lane15) * 64 + ko];
#pragma unroll
      for (int ri = 0; ri < 4; ++ri)
#pragma unroll
        for (int ci = 0; ci < 4; ++ci) acc[ri][ci] = mfma16(av[ri], bv[ci], acc[ri][ci]);
    }
  }
#pragma unroll
  for (int ri = 0; ri < 4; ++ri)
#pragma unroll
    for (int ci = 0; ci < 4; ++ci)
#pragma unroll
      for (int i = 0; i < 4; ++i) {
        const long mrow = brow + wm * 64 + ri * 16 + lgrp * 4 + i;
        const long ncol = bcol + wn * 64 + ci * 16 + lane15;
        const int tq = (int)(mrow >> 4), b = (int)(mrow & 15);
        C[(size_t)b * TT * VOCAB + (size_t)tq * VOCAB + ncol] = acc[ri][ci][i] + b2[ncol];
      }
}

// ---------------- host launch ----------------
extern "C" void kernel_launch(void* const* d_in, const int* in_sizes, int n_in,
                              void* d_out, int out_size, void* d_ws, size_t ws_size,
                              hipStream_t stream) {
  const int* input = (const int*)d_in[0];
  const float* embd = (const float*)d_in[1];
  const float* Wih0 = (const float*)d_in[2];
  const float* Whh0 = (const float*)d_in[3];
  const float* bih0 = (const float*)d_in[4];
  const float* bhh0 = (const float*)d_in[5];
  const float* ln0w = (const float*)d_in[6];
  const float* ln0b = (const float*)d_in[7];
  const float* Wih1 = (const float*)d_in[8];
  const float* Whh1 = (const float*)d_in[9];
  const float* bih1 = (const float*)d_in[10];
  const float* bhh1 = (const float*)d_in[11];
  const float* ln1w = (const float*)d_in[12];
  const float* ln1b = (const float*)d_in[13];
  const float* W1 = (const float*)d_in[14];
  const float* b1 = (const float*)d_in[15];
  const float* ln2w = (const float*)d_in[16];
  const float* ln2b = (const float*)d_in[17];
  const float* W2 = (const float*)d_in[18];
  const float* b2 = (const float*)d_in[19];
  float* out = (float*)d_out;

  // ws (25.4 MB): rings + h1 history + araw + barrier.
  char* ws = (char*)d_ws;
  size_t off = 0;
  auto alloc = [&](size_t bytes) -> char* {
    char* p = ws + off;
    off = (off + bytes + 255) & ~(size_t)255;
    return p;
  };
  double* h0ring = (double*)alloc(2ull * 16 * 1024 * 8);
  double* h1ring = (double*)alloc(2ull * 16 * 1024 * 8);
  float* h1hist = (float*)alloc(4096ull * 1024 * 4);
  short* araw = (short*)alloc(4096ull * 1024 * 2);
  int* bar = (int*)alloc(256);

  hipMemsetAsync(bar, 0, 256, stream);

  // gi0 (100.7 MB f64) in d_out-as-scratch: fully consumed by k_recur; k_head
  // then overwrites every byte of d_out.
  double* gi0 = (double*)d_out;

  k_gi0<<<4096, 256, 0, stream>>>(input, embd, Wih0, bih0, gi0);

  SP A;
  A.Whh0 = Whh0; A.bhh0 = bhh0; A.ln0w = ln0w; A.ln0b = ln0b;
  A.Wih1 = Wih1; A.Whh1 = Whh1; A.bih1 = bih1; A.bhh1 = bhh1;
  A.ln1w = ln1w; A.ln1b = ln1b;
  A.gi0 = gi0; A.h0ring = h0ring; A.h1ring = h1ring; A.h1hist = h1hist;
  A.bar = bar;
  k_recur<<<NBLK, 512, 0, stream>>>(A);

  k_headpre<<<256, 512, 0, stream>>>(h1hist, ln1w, ln1b, W1, b1, araw);

  k_head<<<dim3(250, 32), 256, 0, stream>>>(araw, W2, ln2w, ln2b, b2, out);
}

// Round 13
// 20373.389 us; speedup vs baseline: 1.9687x; 1.9687x over previous
//
#include <hip/hip_runtime.h>
#include <stdint.h>
#include <math.h>

#define TT 256
#define VOCAB 32000
#define LN_EPS 1e-5
#define NBLK 256

typedef __attribute__((ext_vector_type(8))) short bf16x8;
typedef __attribute__((ext_vector_type(4))) float f32x4;

__device__ __forceinline__ float bf2f(short s) {
  return __uint_as_float(((uint32_t)(uint16_t)s) << 16);
}
__device__ __forceinline__ short f2bf(float f) {
  uint32_t u = __float_as_uint(f);
  u += 0x7fffu + ((u >> 16) & 1u);
  return (short)(u >> 16);
}
__device__ __forceinline__ f32x4 mfma16(bf16x8 a, bf16x8 b, f32x4 c) {
  return __builtin_amdgcn_mfma_f32_16x16x32_bf16(a, b, c, 0, 0, 0);
}

// ---------------- gi0 = embd[input] @ Wih0^T + bih0, f64, fully parallel ----------------
__global__ void k_gi0(const int* __restrict__ input, const float* __restrict__ embd,
                      const float* __restrict__ Wih0, const float* __restrict__ bih0,
                      double* __restrict__ gi0) {
  const int t = blockIdx.x >> 4;
  const int cg = blockIdx.x & 15;
  const int tid = threadIdx.x;
  __shared__ float xs[16][512];
  for (int idx = tid; idx < 16 * 512; idx += 256) {
    const int r = idx >> 9, j = idx & 511;
    const int tok = input[r * TT + t];
    xs[r][j] = embd[(size_t)tok * 512 + j];
  }
  __syncthreads();
  const int row = tid >> 4, ct = tid & 15;
  for (int i = 0; i < 12; ++i) {
    const int c = cg * 192 + ct + 16 * i;
    const float4* wp = (const float4*)(Wih0 + (size_t)c * 512);
    const float4* xp = (const float4*)&xs[row][0];
    double acc = 0.0;
#pragma unroll 8
    for (int j4 = 0; j4 < 128; ++j4) {
      const float4 w = wp[j4];
      const float4 x = xp[j4];
      acc = fma((double)x.x, (double)w.x, acc);
      acc = fma((double)x.y, (double)w.y, acc);
      acc = fma((double)x.z, (double)w.z, acc);
      acc = fma((double)x.w, (double)w.w, acc);
    }
    gi0[((size_t)t * 16 + row) * 3072 + c] = acc + (double)bih0[c];
  }
}

// ---------------- persistent recurrence: LDS-RESIDENT WEIGHTS ----------------
// Rounds 9-12 proved the recurrence is weight-delivery-bound, never FMA-bound:
// r9 = 16x redundant L2 reads; r11 = L2 thrash (36MB working set); r12 =
// compiler spilled register-resident weights (VGPR cap 128 -> 4.9GB scratch).
// Fix: 256 blocks x 4 columns-of-both-layers; the block's 36 weight rows
// (12 Whh0 + 12 Wih1 + 12 Whh1) live in LDS f32 (147KB) for all 257 phases,
// loaded from HBM ONCE. Per phase each of 8 waves stages 2 LN-normalized
// batch rows in registers (64 VGPR of f64) and dots them against all 36 LDS
// rows (f64 FMA, stride-8B float2 reads = free 2-way). LN0(h0[p-1]) is
// consumed by BOTH L0(t=p) and L1-ih(t=p-1) -> staged once.
struct SP {
  const float *Whh0, *bhh0, *ln0w, *ln0b;
  const float *Wih1, *Whh1, *bih1, *bhh1, *ln1w, *ln1b;
  const double* gi0;
  double *h0ring, *h1ring;  // [2][16][1024] f64 raw hidden states
  float* h1hist;            // [256*16][1024] f32 raw h1 history
  int* bar;
};

// stage one batch row: lane l holds k = jj*128 + l*2 + u. LN via 6-step shfl.
__device__ __forceinline__ void stageR(const double* __restrict__ hrow,
                                       const float* __restrict__ lnw,
                                       const float* __restrict__ lnb,
                                       const int l, double* __restrict__ a,
                                       double& m_out, double& rs_out) {
  double s = 0.0, q = 0.0;
#pragma unroll
  for (int jj = 0; jj < 8; ++jj) {
    const double2 x = *(const double2*)(hrow + jj * 128 + l * 2);
    a[jj*2] = x.x; a[jj*2+1] = x.y;
    s += x.x + x.y; q += x.x*x.x + x.y*x.y;
  }
#pragma unroll
  for (int mk = 1; mk <= 32; mk <<= 1) { s += __shfl_xor(s, mk); q += __shfl_xor(q, mk); }
  const double m = s * (1.0 / 1024.0);
  const double rs = 1.0 / sqrt(q * (1.0 / 1024.0) - m * m + LN_EPS);
#pragma unroll
  for (int jj = 0; jj < 8; ++jj) {
    const float2 lw = *(const float2*)(lnw + jj * 128 + l * 2);
    const float2 lb = *(const float2*)(lnb + jj * 128 + l * 2);
    a[jj*2]   = (a[jj*2]   - m) * rs * (double)lw.x + (double)lb.x;
    a[jj*2+1] = (a[jj*2+1] - m) * rs * (double)lw.y + (double)lb.y;
  }
  m_out = m; rs_out = rs;
}

__launch_bounds__(512, 1)
__global__ void k_recur(SP A) {
  __shared__ float wlds[36][1024];   // 147456 B weight slice (f32)
  __shared__ double sPre[36][16];    // dot sums [weight-row][batch-row]
  __shared__ double sM0[16], sR0[16], sM1[16], sR1[16];
  const int tid = threadIdx.x;
  const int w = tid >> 6;  // wave 0..7 -> batch rows 2w, 2w+1
  const int l = tid & 63;
  const int bid = blockIdx.x;
  const int col0 = bid * 4;

  // ---- one-time: weight slice -> LDS. j<12: Whh0; 12..23: Wih1; 24..35: Whh1
  for (int idx = tid; idx < 36 * 1024; idx += 512) {
    const int j = idx >> 10, k = idx & 1023;
    const int jj = (j < 12) ? j : (j < 24 ? j - 12 : j - 24);
    const int g = jj % 3, ci = jj / 3;
    const float* W = (j < 12) ? A.Whh0 : (j < 24 ? A.Wih1 : A.Whh1);
    wlds[j][k] = W[(size_t)(g * 1024 + col0 + ci) * 1024 + k];
  }
  __syncthreads();

  for (int p = 0; p <= TT; ++p) {
    const bool doL0 = (p < TT);
    const int t1 = p - 1;
    double ar0[16], ar1[16];

    if (p >= 1) {
      // a0 = LN0(h0[p-1]) -- feeds L0(t=p) Whh0-dots AND L1(t=p-1) Wih1-dots
      const double* base = A.h0ring + (size_t)((p - 1) & 1) * 16384;
      double ma, ra, mb, rb;
      stageR(base + (2 * w) * 1024, A.ln0w, A.ln0b, l, ar0, ma, ra);
      stageR(base + (2 * w + 1) * 1024, A.ln0w, A.ln0b, l, ar1, mb, rb);
      if (l == 0) { sM0[2*w] = ma; sR0[2*w] = ra; sM0[2*w+1] = mb; sR0[2*w+1] = rb; }
      const int j0 = doL0 ? 0 : 12;
      for (int j = j0; j < 24; ++j) {
        double c0 = 0.0, c1 = 0.0;
#pragma unroll
        for (int jj = 0; jj < 8; ++jj) {
          const float2 wv = *(const float2*)&wlds[j][jj * 128 + l * 2];
          const double wx = (double)wv.x, wy = (double)wv.y;
          c0 = fma(wx, ar0[jj*2], c0); c0 = fma(wy, ar0[jj*2+1], c0);
          c1 = fma(wx, ar1[jj*2], c1); c1 = fma(wy, ar1[jj*2+1], c1);
        }
#pragma unroll
        for (int mk = 1; mk <= 32; mk <<= 1) { c0 += __shfl_xor(c0, mk); c1 += __shfl_xor(c1, mk); }
        if (l == 0) { sPre[j][2*w] = c0; sPre[j][2*w+1] = c1; }
      }
      if (t1 > 0) {
        // a1 = LN1(h1[p-2]) -> Whh1 dots (reuses ar0/ar1 registers)
        const double* base1 = A.h1ring + (size_t)((t1 - 1) & 1) * 16384;
        stageR(base1 + (2 * w) * 1024, A.ln1w, A.ln1b, l, ar0, ma, ra);
        stageR(base1 + (2 * w + 1) * 1024, A.ln1w, A.ln1b, l, ar1, mb, rb);
        if (l == 0) { sM1[2*w] = ma; sR1[2*w] = ra; sM1[2*w+1] = mb; sR1[2*w+1] = rb; }
        for (int j = 24; j < 36; ++j) {
          double c0 = 0.0, c1 = 0.0;
#pragma unroll
          for (int jj = 0; jj < 8; ++jj) {
            const float2 wv = *(const float2*)&wlds[j][jj * 128 + l * 2];
            const double wx = (double)wv.x, wy = (double)wv.y;
            c0 = fma(wx, ar0[jj*2], c0); c0 = fma(wy, ar0[jj*2+1], c0);
            c1 = fma(wx, ar1[jj*2], c1); c1 = fma(wy, ar1[jj*2+1], c1);
          }
#pragma unroll
          for (int mk = 1; mk <= 32; mk <<= 1) { c0 += __shfl_xor(c0, mk); c1 += __shfl_xor(c1, mk); }
          if (l == 0) { sPre[j][2*w] = c0; sPre[j][2*w+1] = c1; }
        }
      }
    }
    __syncthreads();

    // ---- gates: L0 on threads 0..63, L1 on threads 64..127 ----
    if (doL0 && tid < 64) {
      const int r = tid >> 2, ci = tid & 3;
      const int c = col0 + ci;
      const int t0 = p;
      double ghr, ghz, ghn, hprev;
      if (t0 > 0) {
        ghr = sPre[ci*3+0][r] + (double)A.bhh0[c];
        ghz = sPre[ci*3+1][r] + (double)A.bhh0[c + 1024];
        ghn = sPre[ci*3+2][r] + (double)A.bhh0[c + 2048];
        const double praw = A.h0ring[(size_t)((t0 - 1) & 1) * 16384 + r * 1024 + c];
        hprev = (praw - sM0[r]) * sR0[r] * (double)A.ln0w[c] + (double)A.ln0b[c];
      } else {
        ghr = (double)A.bhh0[c]; ghz = (double)A.bhh0[c + 1024]; ghn = (double)A.bhh0[c + 2048];
        hprev = 0.0;
      }
      const double* gp = A.gi0 + ((size_t)t0 * 16 + r) * 3072 + c;
      const double gir = gp[0], giz = gp[1024], gin = gp[2048];
      const double rg = 1.0 / (1.0 + exp(-(gir + ghr)));
      const double zg = 1.0 / (1.0 + exp(-(giz + ghz)));
      const double ng = tanh(gin + rg * ghn);
      A.h0ring[(size_t)(t0 & 1) * 16384 + r * 1024 + c] = (1.0 - zg) * ng + zg * hprev;
    }
    if (t1 >= 0 && tid >= 64 && tid < 128) {
      const int r = (tid - 64) >> 2, ci = (tid - 64) & 3;
      const int c = col0 + ci;
      const double gir = sPre[12+ci*3+0][r] + (double)A.bih1[c];
      const double giz = sPre[12+ci*3+1][r] + (double)A.bih1[c + 1024];
      const double gin = sPre[12+ci*3+2][r] + (double)A.bih1[c + 2048];
      double ghr, ghz, ghn, hprev;
      if (t1 > 0) {
        ghr = sPre[24+ci*3+0][r] + (double)A.bhh1[c];
        ghz = sPre[24+ci*3+1][r] + (double)A.bhh1[c + 1024];
        ghn = sPre[24+ci*3+2][r] + (double)A.bhh1[c + 2048];
        const double praw = A.h1ring[(size_t)((t1 - 1) & 1) * 16384 + r * 1024 + c];
        hprev = (praw - sM1[r]) * sR1[r] * (double)A.ln1w[c] + (double)A.ln1b[c];
      } else {
        ghr = (double)A.bhh1[c]; ghz = (double)A.bhh1[c + 1024]; ghn = (double)A.bhh1[c + 2048];
        hprev = 0.0;
      }
      const double rg = 1.0 / (1.0 + exp(-(gir + ghr)));
      const double zg = 1.0 / (1.0 + exp(-(giz + ghz)));
      const double ng = tanh(gin + rg * ghn);
      const double hnew = (1.0 - zg) * ng + zg * hprev;
      A.h1ring[(size_t)(t1 & 1) * 16384 + r * 1024 + c] = hnew;
      A.h1hist[((size_t)t1 * 16 + r) * 1024 + c] = (float)hnew;
    }

    // ---------- grid barrier ----------
    __syncthreads();
    if (tid == 0) {
      __threadfence();
      __hip_atomic_fetch_add(A.bar, 1, __ATOMIC_ACQ_REL, __HIP_MEMORY_SCOPE_AGENT);
      const int target = NBLK * (p + 1);
      while (__hip_atomic_load(A.bar, __ATOMIC_ACQUIRE, __HIP_MEMORY_SCOPE_AGENT) < target) {
        __builtin_amdgcn_s_sleep(2);
      }
      __threadfence();
    }
    __syncthreads();
  }
}

// ---------------- batched head pre-proj (byte-identical to rounds 7-12) ----------------
__launch_bounds__(512, 2)
__global__ void k_headpre(const float* __restrict__ h1hist, const float* __restrict__ ln1w,
                          const float* __restrict__ ln1b, const float* __restrict__ W1,
                          const float* __restrict__ b1, short* __restrict__ araw) {
  const int tid = threadIdx.x;
  const int row = tid >> 5, ks = tid & 31;
  const size_t m = (size_t)blockIdx.x * 16 + row;
  const float* hp = h1hist + m * 1024;
  float a[32];
  float s = 0.f, q = 0.f;
#pragma unroll
  for (int g = 0; g < 8; ++g) {
    const float4 v = *(const float4*)(hp + g * 128 + ks * 4);
    a[g*4+0] = v.x; a[g*4+1] = v.y; a[g*4+2] = v.z; a[g*4+3] = v.w;
    s += v.x + v.y + v.z + v.w;
    q += v.x * v.x + v.y * v.y + v.z * v.z + v.w * v.w;
  }
#pragma unroll
  for (int mk = 1; mk <= 16; mk <<= 1) { s += __shfl_xor(s, mk); q += __shfl_xor(q, mk); }
  const float mn = s * (1.f / 1024.f);
  const float rs = rsqrtf(q * (1.f / 1024.f) - mn * mn + 1e-5f);
#pragma unroll
  for (int g = 0; g < 8; ++g) {
    const float4 lw = *(const float4*)(ln1w + g * 128 + ks * 4);
    const float4 lb = *(const float4*)(ln1b + g * 128 + ks * 4);
    a[g*4+0] = (a[g*4+0] - mn) * rs * lw.x + lb.x;
    a[g*4+1] = (a[g*4+1] - mn) * rs * lw.y + lb.y;
    a[g*4+2] = (a[g*4+2] - mn) * rs * lw.z + lb.z;
    a[g*4+3] = (a[g*4+3] - mn) * rs * lw.w + lb.w;
  }
  for (int c = 0; c < 1024; ++c) {
    const float4* wp = (const float4*)(W1 + (size_t)c * 1024);
    float acc = 0.f;
#pragma unroll
    for (int g = 0; g < 8; ++g) {
      const float4 w = wp[g * 32 + ks];
      acc = fmaf(a[g*4+0], w.x, acc); acc = fmaf(a[g*4+1], w.y, acc);
      acc = fmaf(a[g*4+2], w.z, acc); acc = fmaf(a[g*4+3], w.w, acc);
    }
#pragma unroll
    for (int mk = 1; mk <= 16; mk <<= 1) acc += __shfl_xor(acc, mk);
    if (ks == 0) {
      const float y = acc + b1[c];
      araw[m * 1024 + c] = f2bf(y > 0.f ? y : 0.01f * y);
    }
  }
}

// ---------------- head GEMM (byte-identical to rounds 6-12) ----------------
__global__ void k_head(const short* __restrict__ araw, const float* __restrict__ W2,
                       const float* __restrict__ ln2w, const float* __restrict__ ln2b,
                       const float* __restrict__ b2, float* __restrict__ C) {
  __shared__ __align__(16) short As[128 * 64];
  __shared__ __align__(16) short Bs[128 * 64];
  __shared__ float rowm[128], rowr[128];
  __shared__ float lnw_s[1024], lnb_s[1024];
  __shared__ float ps[256], pq[256];
  const int tid = threadIdx.x;
  const long brow = (long)blockIdx.y * 128;
  const long bcol = (long)blockIdx.x * 128;

  for (int i = tid; i < 1024; i += 256) { lnw_s[i] = ln2w[i]; lnb_s[i] = ln2b[i]; }
  {
    const int r2 = tid >> 1, hf = tid & 1;
    const short* ap = araw + (brow + r2) * 1024 + hf * 512;
    float s = 0.f, q = 0.f;
    for (int j = 0; j < 512; j += 8) {
      const bf16x8 v = *(const bf16x8*)(ap + j);
#pragma unroll
      for (int e = 0; e < 8; ++e) { const float x = bf2f(v[e]); s += x; q += x * x; }
    }
    ps[tid] = s; pq[tid] = q;
  }
  __syncthreads();
  if (tid < 128) {
    const float s = ps[2 * tid] + ps[2 * tid + 1];
    const float q = pq[2 * tid] + pq[2 * tid + 1];
    const float m = s * (1.f / 1024.f);
    rowm[tid] = m;
    rowr[tid] = rsqrtf(q * (1.f / 1024.f) - m * m + 1e-5f);
  }
  __syncthreads();

  const int l = tid & 63;
  const int w = tid >> 6;
  const int wm = w >> 1, wn = w & 1;
  const int lane15 = l & 15, lgrp = l >> 4;
  f32x4 zero4 = {0.f, 0.f, 0.f, 0.f};
  f32x4 acc[4][4];
#pragma unroll
  for (int ri = 0; ri < 4; ++ri)
#pragma unroll
    for (int ci = 0; ci < 4; ++ci) acc[ri][ci] = zero4;

  for (int k0 = 0; k0 < 1024; k0 += 64) {
    __syncthreads();
#pragma unroll
    for (int i = 0; i < 4; ++i) {
      const int c = tid + i * 256;
      const int r = c >> 3, cc = c & 7;
      const int k = k0 + cc * 8;
      {
        const bf16x8 v = *(const bf16x8*)(araw + (brow + r) * 1024 + k);
        const float mm = rowm[r], rr = rowr[r];
        bf16x8 o;
#pragma unroll
        for (int e = 0; e < 8; ++e)
          o[e] = f2bf((bf2f(v[e]) - mm) * rr * lnw_s[k + e] + lnb_s[k + e]);
        *(bf16x8*)&As[r * 64 + cc * 8] = o;
      }
      {
        const float4* bp = (const float4*)(W2 + (bcol + r) * 1024 + k);
        const float4 v0 = bp[0], v1 = bp[1];
        bf16x8 o;
        o[0] = f2bf(v0.x); o[1] = f2bf(v0.y); o[2] = f2bf(v0.z); o[3] = f2bf(v0.w);
        o[4] = f2bf(v1.x); o[5] = f2bf(v1.y); o[6] = f2bf(v1.z); o[7] = f2bf(v1.w);
        *(bf16x8*)&Bs[r * 64 + cc * 8] = o;
      }
    }
    __syncthreads();
#pragma unroll
    for (int kk = 0; kk < 2; ++kk) {
      const int ko = kk * 32 + lgrp * 8;
      bf16x8 av[4], bv[4];
#pragma unroll
      for (int ri = 0; ri < 4; ++ri) av[ri] = *(const bf16x8*)&As[(wm * 64 + ri * 16 + lane15) * 64 + ko];
#pragma unroll
      for (int ci = 0; ci < 4; ++ci) bv[ci] = *(const bf16x8*)&Bs[(wn * 64 + ci * 16 + lane15) * 64 + ko];
#pragma unroll
      for (int ri = 0; ri < 4; ++ri)
#pragma unroll
        for (int ci = 0; ci < 4; ++ci) acc[ri][ci] = mfma16(av[ri], bv[ci], acc[ri][ci]);
    }
  }
#pragma unroll
  for (int ri = 0; ri < 4; ++ri)
#pragma unroll
    for (int ci = 0; ci < 4; ++ci)
#pragma unroll
      for (int i = 0; i < 4; ++i) {
        const long mrow = brow + wm * 64 + ri * 16 + lgrp * 4 + i;
        const long ncol = bcol + wn * 64 + ci * 16 + lane15;
        const int tq = (int)(mrow >> 4), b = (int)(mrow & 15);
        C[(size_t)b * TT * VOCAB + (size_t)tq * VOCAB + ncol] = acc[ri][ci][i] + b2[ncol];
      }
}

// ---------------- host launch ----------------
extern "C" void kernel_launch(void* const* d_in, const int* in_sizes, int n_in,
                              void* d_out, int out_size, void* d_ws, size_t ws_size,
                              hipStream_t stream) {
  const int* input = (const int*)d_in[0];
  const float* embd = (const float*)d_in[1];
  const float* Wih0 = (const float*)d_in[2];
  const float* Whh0 = (const float*)d_in[3];
  const float* bih0 = (const float*)d_in[4];
  const float* bhh0 = (const float*)d_in[5];
  const float* ln0w = (const float*)d_in[6];
  const float* ln0b = (const float*)d_in[7];
  const float* Wih1 = (const float*)d_in[8];
  const float* Whh1 = (const float*)d_in[9];
  const float* bih1 = (const float*)d_in[10];
  const float* bhh1 = (const float*)d_in[11];
  const float* ln1w = (const float*)d_in[12];
  const float* ln1b = (const float*)d_in[13];
  const float* W1 = (const float*)d_in[14];
  const float* b1 = (const float*)d_in[15];
  const float* ln2w = (const float*)d_in[16];
  const float* ln2b = (const float*)d_in[17];
  const float* W2 = (const float*)d_in[18];
  const float* b2 = (const float*)d_in[19];
  float* out = (float*)d_out;

  // ws (25.4 MB): rings + h1 history + araw + barrier.
  char* ws = (char*)d_ws;
  size_t off = 0;
  auto alloc = [&](size_t bytes) -> char* {
    char* p = ws + off;
    off = (off + bytes + 255) & ~(size_t)255;
    return p;
  };
  double* h0ring = (double*)alloc(2ull * 16 * 1024 * 8);
  double* h1ring = (double*)alloc(2ull * 16 * 1024 * 8);
  float* h1hist = (float*)alloc(4096ull * 1024 * 4);
  short* araw = (short*)alloc(4096ull * 1024 * 2);
  int* bar = (int*)alloc(256);

  hipMemsetAsync(bar, 0, 256, stream);

  // gi0 (100.7 MB f64) in d_out-as-scratch: fully consumed by k_recur; k_head
  // then overwrites every byte of d_out.
  double* gi0 = (double*)d_out;

  k_gi0<<<4096, 256, 0, stream>>>(input, embd, Wih0, bih0, gi0);

  SP A;
  A.Whh0 = Whh0; A.bhh0 = bhh0; A.ln0w = ln0w; A.ln0b = ln0b;
  A.Wih1 = Wih1; A.Whh1 = Whh1; A.bih1 = bih1; A.bhh1 = bhh1;
  A.ln1w = ln1w; A.ln1b = ln1b;
  A.gi0 = gi0; A.h0ring = h0ring; A.h1ring = h1ring; A.h1hist = h1hist;
  A.bar = bar;
  k_recur<<<NBLK, 512, 0, stream>>>(A);

  k_headpre<<<256, 512, 0, stream>>>(h1hist, ln1w, ln1b, W1, b1, araw);

  k_head<<<dim3(250, 32), 256, 0, stream>>>(araw, W2, ln2w, ln2b, b2, out);
}

// Round 14
// 15993.153 us; speedup vs baseline: 2.5079x; 1.2739x over previous
//
#include <hip/hip_runtime.h>
#include <stdint.h>
#include <math.h>

#define TT 256
#define VOCAB 32000
#define LN_EPS 1e-5
#define NBLK 256

typedef __attribute__((ext_vector_type(8))) short bf16x8;
typedef __attribute__((ext_vector_type(4))) float f32x4;

__device__ __forceinline__ float bf2f(short s) {
  return __uint_as_float(((uint32_t)(uint16_t)s) << 16);
}
__device__ __forceinline__ short f2bf(float f) {
  uint32_t u = __float_as_uint(f);
  u += 0x7fffu + ((u >> 16) & 1u);
  return (short)(u >> 16);
}
__device__ __forceinline__ f32x4 mfma16(bf16x8 a, bf16x8 b, f32x4 c) {
  return __builtin_amdgcn_mfma_f32_16x16x32_bf16(a, b, c, 0, 0, 0);
}

// coherent (L2-bypassing) h-ring access: relaxed agent-scope atomics go to the
// coherent point (L3), so cross-XCD visibility needs NO agent fences (which
// on gfx950 cost whole-L2 writeback/invalidate -- the ~40us/phase stall of r13).
__device__ __forceinline__ double cload(const double* p) {
  return __hip_atomic_load(p, __ATOMIC_RELAXED, __HIP_MEMORY_SCOPE_AGENT);
}
__device__ __forceinline__ void cstore(double* p, double v) {
  __hip_atomic_store(p, v, __ATOMIC_RELAXED, __HIP_MEMORY_SCOPE_AGENT);
}

// ---------------- gi0 = embd[input] @ Wih0^T + bih0, f64, fully parallel ----------------
__global__ void k_gi0(const int* __restrict__ input, const float* __restrict__ embd,
                      const float* __restrict__ Wih0, const float* __restrict__ bih0,
                      double* __restrict__ gi0) {
  const int t = blockIdx.x >> 4;
  const int cg = blockIdx.x & 15;
  const int tid = threadIdx.x;
  __shared__ float xs[16][512];
  for (int idx = tid; idx < 16 * 512; idx += 256) {
    const int r = idx >> 9, j = idx & 511;
    const int tok = input[r * TT + t];
    xs[r][j] = embd[(size_t)tok * 512 + j];
  }
  __syncthreads();
  const int row = tid >> 4, ct = tid & 15;
  for (int i = 0; i < 12; ++i) {
    const int c = cg * 192 + ct + 16 * i;
    const float4* wp = (const float4*)(Wih0 + (size_t)c * 512);
    const float4* xp = (const float4*)&xs[row][0];
    double acc = 0.0;
#pragma unroll 8
    for (int j4 = 0; j4 < 128; ++j4) {
      const float4 w = wp[j4];
      const float4 x = xp[j4];
      acc = fma((double)x.x, (double)w.x, acc);
      acc = fma((double)x.y, (double)w.y, acc);
      acc = fma((double)x.z, (double)w.z, acc);
      acc = fma((double)x.w, (double)w.w, acc);
    }
    gi0[((size_t)t * 16 + row) * 3072 + c] = acc + (double)bih0[c];
  }
}

// ---------------- persistent recurrence: LDS weights + FENCE-FREE barrier ----------------
struct SP {
  const float *Whh0, *bhh0, *ln0w, *ln0b;
  const float *Wih1, *Whh1, *bih1, *bhh1, *ln1w, *ln1b;
  const double* gi0;
  double *h0ring, *h1ring;  // [2][16][1024] f64 raw hidden states (coherent access)
  float* h1hist;            // [256*16][1024] f32 raw h1 history (plain stores)
  int* bar;
};

// stage one batch row via coherent loads; LN math bit-identical to r13.
__device__ __forceinline__ void stageC(const double* __restrict__ hrow,
                                       const float* __restrict__ lnw,
                                       const float* __restrict__ lnb,
                                       const int l, double* __restrict__ a,
                                       double& m_out, double& rs_out) {
  double s = 0.0, q = 0.0;
#pragma unroll
  for (int jj = 0; jj < 8; ++jj) {
    const double x0 = cload(hrow + jj * 128 + l * 2);
    const double x1 = cload(hrow + jj * 128 + l * 2 + 1);
    a[jj*2] = x0; a[jj*2+1] = x1;
    s += x0 + x1; q += x0*x0 + x1*x1;
  }
#pragma unroll
  for (int mk = 1; mk <= 32; mk <<= 1) { s += __shfl_xor(s, mk); q += __shfl_xor(q, mk); }
  const double m = s * (1.0 / 1024.0);
  const double rs = 1.0 / sqrt(q * (1.0 / 1024.0) - m * m + LN_EPS);
#pragma unroll
  for (int jj = 0; jj < 8; ++jj) {
    const float2 lw = *(const float2*)(lnw + jj * 128 + l * 2);
    const float2 lb = *(const float2*)(lnb + jj * 128 + l * 2);
    a[jj*2]   = (a[jj*2]   - m) * rs * (double)lw.x + (double)lb.x;
    a[jj*2+1] = (a[jj*2+1] - m) * rs * (double)lw.y + (double)lb.y;
  }
  m_out = m; rs_out = rs;
}

__launch_bounds__(512, 1)
__global__ void k_recur(SP A) {
  __shared__ float wlds[36][1024];   // 147456 B weight slice (f32), resident all phases
  __shared__ double sPre[36][16];    // dot sums [weight-row][batch-row]
  __shared__ double sM0[16], sR0[16], sM1[16], sR1[16];
  const int tid = threadIdx.x;
  const int w = tid >> 6;  // wave 0..7 -> batch rows 2w, 2w+1
  const int l = tid & 63;
  const int bid = blockIdx.x;
  const int col0 = bid * 4;

  // ---- one-time: weight slice -> LDS. j<12: Whh0; 12..23: Wih1; 24..35: Whh1
  for (int idx = tid; idx < 36 * 1024; idx += 512) {
    const int j = idx >> 10, k = idx & 1023;
    const int jj = (j < 12) ? j : (j < 24 ? j - 12 : j - 24);
    const int g = jj % 3, ci = jj / 3;
    const float* W = (j < 12) ? A.Whh0 : (j < 24 ? A.Wih1 : A.Whh1);
    wlds[j][k] = W[(size_t)(g * 1024 + col0 + ci) * 1024 + k];
  }
  __syncthreads();

  for (int p = 0; p <= TT; ++p) {
    const bool doL0 = (p < TT);
    const int t1 = p - 1;
    double ar0[16], ar1[16];

    if (p >= 1) {
      // a0 = LN0(h0[p-1]) -- feeds L0(t=p) Whh0-dots AND L1(t=p-1) Wih1-dots
      const double* base = A.h0ring + (size_t)((p - 1) & 1) * 16384;
      double ma, ra, mb, rb;
      stageC(base + (2 * w) * 1024, A.ln0w, A.ln0b, l, ar0, ma, ra);
      stageC(base + (2 * w + 1) * 1024, A.ln0w, A.ln0b, l, ar1, mb, rb);
      if (l == 0) { sM0[2*w] = ma; sR0[2*w] = ra; sM0[2*w+1] = mb; sR0[2*w+1] = rb; }
      const int j0 = doL0 ? 0 : 12;
      for (int j = j0; j < 24; ++j) {
        double c0 = 0.0, c1 = 0.0;
#pragma unroll
        for (int jj = 0; jj < 8; ++jj) {
          const float2 wv = *(const float2*)&wlds[j][jj * 128 + l * 2];
          const double wx = (double)wv.x, wy = (double)wv.y;
          c0 = fma(wx, ar0[jj*2], c0); c0 = fma(wy, ar0[jj*2+1], c0);
          c1 = fma(wx, ar1[jj*2], c1); c1 = fma(wy, ar1[jj*2+1], c1);
        }
#pragma unroll
        for (int mk = 1; mk <= 32; mk <<= 1) { c0 += __shfl_xor(c0, mk); c1 += __shfl_xor(c1, mk); }
        if (l == 0) { sPre[j][2*w] = c0; sPre[j][2*w+1] = c1; }
      }
      if (t1 > 0) {
        // a1 = LN1(h1[p-2]) -> Whh1 dots (reuses ar0/ar1 registers)
        const double* base1 = A.h1ring + (size_t)((t1 - 1) & 1) * 16384;
        stageC(base1 + (2 * w) * 1024, A.ln1w, A.ln1b, l, ar0, ma, ra);
        stageC(base1 + (2 * w + 1) * 1024, A.ln1w, A.ln1b, l, ar1, mb, rb);
        if (l == 0) { sM1[2*w] = ma; sR1[2*w] = ra; sM1[2*w+1] = mb; sR1[2*w+1] = rb; }
        for (int j = 24; j < 36; ++j) {
          double c0 = 0.0, c1 = 0.0;
#pragma unroll
          for (int jj = 0; jj < 8; ++jj) {
            const float2 wv = *(const float2*)&wlds[j][jj * 128 + l * 2];
            const double wx = (double)wv.x, wy = (double)wv.y;
            c0 = fma(wx, ar0[jj*2], c0); c0 = fma(wy, ar0[jj*2+1], c0);
            c1 = fma(wx, ar1[jj*2], c1); c1 = fma(wy, ar1[jj*2+1], c1);
          }
#pragma unroll
          for (int mk = 1; mk <= 32; mk <<= 1) { c0 += __shfl_xor(c0, mk); c1 += __shfl_xor(c1, mk); }
          if (l == 0) { sPre[j][2*w] = c0; sPre[j][2*w+1] = c1; }
        }
      }
    }
    __syncthreads();

    // ---- gates: L0 on threads 0..63, L1 on threads 64..127 ----
    if (doL0 && tid < 64) {
      const int r = tid >> 2, ci = tid & 3;
      const int c = col0 + ci;
      const int t0 = p;
      double ghr, ghz, ghn, hprev;
      if (t0 > 0) {
        ghr = sPre[ci*3+0][r] + (double)A.bhh0[c];
        ghz = sPre[ci*3+1][r] + (double)A.bhh0[c + 1024];
        ghn = sPre[ci*3+2][r] + (double)A.bhh0[c + 2048];
        const double praw = cload(A.h0ring + (size_t)((t0 - 1) & 1) * 16384 + r * 1024 + c);
        hprev = (praw - sM0[r]) * sR0[r] * (double)A.ln0w[c] + (double)A.ln0b[c];
      } else {
        ghr = (double)A.bhh0[c]; ghz = (double)A.bhh0[c + 1024]; ghn = (double)A.bhh0[c + 2048];
        hprev = 0.0;
      }
      const double* gp = A.gi0 + ((size_t)t0 * 16 + r) * 3072 + c;
      const double gir = gp[0], giz = gp[1024], gin = gp[2048];
      const double rg = 1.0 / (1.0 + exp(-(gir + ghr)));
      const double zg = 1.0 / (1.0 + exp(-(giz + ghz)));
      const double ng = tanh(gin + rg * ghn);
      cstore(A.h0ring + (size_t)(t0 & 1) * 16384 + r * 1024 + c, (1.0 - zg) * ng + zg * hprev);
    }
    if (t1 >= 0 && tid >= 64 && tid < 128) {
      const int r = (tid - 64) >> 2, ci = (tid - 64) & 3;
      const int c = col0 + ci;
      const double gir = sPre[12+ci*3+0][r] + (double)A.bih1[c];
      const double giz = sPre[12+ci*3+1][r] + (double)A.bih1[c + 1024];
      const double gin = sPre[12+ci*3+2][r] + (double)A.bih1[c + 2048];
      double ghr, ghz, ghn, hprev;
      if (t1 > 0) {
        ghr = sPre[24+ci*3+0][r] + (double)A.bhh1[c];
        ghz = sPre[24+ci*3+1][r] + (double)A.bhh1[c + 1024];
        ghn = sPre[24+ci*3+2][r] + (double)A.bhh1[c + 2048];
        const double praw = cload(A.h1ring + (size_t)((t1 - 1) & 1) * 16384 + r * 1024 + c);
        hprev = (praw - sM1[r]) * sR1[r] * (double)A.ln1w[c] + (double)A.ln1b[c];
      } else {
        ghr = (double)A.bhh1[c]; ghz = (double)A.bhh1[c + 1024]; ghn = (double)A.bhh1[c + 2048];
        hprev = 0.0;
      }
      const double rg = 1.0 / (1.0 + exp(-(gir + ghr)));
      const double zg = 1.0 / (1.0 + exp(-(giz + ghz)));
      const double ng = tanh(gin + rg * ghn);
      const double hnew = (1.0 - zg) * ng + zg * hprev;
      cstore(A.h1ring + (size_t)(t1 & 1) * 16384 + r * 1024 + c, hnew);
      A.h1hist[((size_t)t1 * 16 + r) * 1024 + c] = (float)hnew;
    }

    // ---------- fence-free grid barrier ----------
    // __syncthreads drains each wave's vmcnt (coherent stores completed at the
    // coherent point) before block 0 announces arrival. Spinners poll with
    // relaxed agent loads; h-ring reads next phase are coherent loads, so no
    // L2 invalidate is needed. NO agent-scope fences anywhere.
    __syncthreads();
    if (tid == 0) {
      __hip_atomic_fetch_add(A.bar, 1, __ATOMIC_RELAXED, __HIP_MEMORY_SCOPE_AGENT);
      const int target = NBLK * (p + 1);
      while (__hip_atomic_load(A.bar, __ATOMIC_RELAXED, __HIP_MEMORY_SCOPE_AGENT) < target) {
        __builtin_amdgcn_s_sleep(2);
      }
    }
    __syncthreads();
  }
}

// ---------------- batched head pre-proj (byte-identical to rounds 7-13) ----------------
__launch_bounds__(512, 2)
__global__ void k_headpre(const float* __restrict__ h1hist, const float* __restrict__ ln1w,
                          const float* __restrict__ ln1b, const float* __restrict__ W1,
                          const float* __restrict__ b1, short* __restrict__ araw) {
  const int tid = threadIdx.x;
  const int row = tid >> 5, ks = tid & 31;
  const size_t m = (size_t)blockIdx.x * 16 + row;
  const float* hp = h1hist + m * 1024;
  float a[32];
  float s = 0.f, q = 0.f;
#pragma unroll
  for (int g = 0; g < 8; ++g) {
    const float4 v = *(const float4*)(hp + g * 128 + ks * 4);
    a[g*4+0] = v.x; a[g*4+1] = v.y; a[g*4+2] = v.z; a[g*4+3] = v.w;
    s += v.x + v.y + v.z + v.w;
    q += v.x * v.x + v.y * v.y + v.z * v.z + v.w * v.w;
  }
#pragma unroll
  for (int mk = 1; mk <= 16; mk <<= 1) { s += __shfl_xor(s, mk); q += __shfl_xor(q, mk); }
  const float mn = s * (1.f / 1024.f);
  const float rs = rsqrtf(q * (1.f / 1024.f) - mn * mn + 1e-5f);
#pragma unroll
  for (int g = 0; g < 8; ++g) {
    const float4 lw = *(const float4*)(ln1w + g * 128 + ks * 4);
    const float4 lb = *(const float4*)(ln1b + g * 128 + ks * 4);
    a[g*4+0] = (a[g*4+0] - mn) * rs * lw.x + lb.x;
    a[g*4+1] = (a[g*4+1] - mn) * rs * lw.y + lb.y;
    a[g*4+2] = (a[g*4+2] - mn) * rs * lw.z + lb.z;
    a[g*4+3] = (a[g*4+3] - mn) * rs * lw.w + lb.w;
  }
  for (int c = 0; c < 1024; ++c) {
    const float4* wp = (const float4*)(W1 + (size_t)c * 1024);
    float acc = 0.f;
#pragma unroll
    for (int g = 0; g < 8; ++g) {
      const float4 w = wp[g * 32 + ks];
      acc = fmaf(a[g*4+0], w.x, acc); acc = fmaf(a[g*4+1], w.y, acc);
      acc = fmaf(a[g*4+2], w.z, acc); acc = fmaf(a[g*4+3], w.w, acc);
    }
#pragma unroll
    for (int mk = 1; mk <= 16; mk <<= 1) acc += __shfl_xor(acc, mk);
    if (ks == 0) {
      const float y = acc + b1[c];
      araw[m * 1024 + c] = f2bf(y > 0.f ? y : 0.01f * y);
    }
  }
}

// ---------------- head GEMM (byte-identical to rounds 6-13) ----------------
__global__ void k_head(const short* __restrict__ araw, const float* __restrict__ W2,
                       const float* __restrict__ ln2w, const float* __restrict__ ln2b,
                       const float* __restrict__ b2, float* __restrict__ C) {
  __shared__ __align__(16) short As[128 * 64];
  __shared__ __align__(16) short Bs[128 * 64];
  __shared__ float rowm[128], rowr[128];
  __shared__ float lnw_s[1024], lnb_s[1024];
  __shared__ float ps[256], pq[256];
  const int tid = threadIdx.x;
  const long brow = (long)blockIdx.y * 128;
  const long bcol = (long)blockIdx.x * 128;

  for (int i = tid; i < 1024; i += 256) { lnw_s[i] = ln2w[i]; lnb_s[i] = ln2b[i]; }
  {
    const int r2 = tid >> 1, hf = tid & 1;
    const short* ap = araw + (brow + r2) * 1024 + hf * 512;
    float s = 0.f, q = 0.f;
    for (int j = 0; j < 512; j += 8) {
      const bf16x8 v = *(const bf16x8*)(ap + j);
#pragma unroll
      for (int e = 0; e < 8; ++e) { const float x = bf2f(v[e]); s += x; q += x * x; }
    }
    ps[tid] = s; pq[tid] = q;
  }
  __syncthreads();
  if (tid < 128) {
    const float s = ps[2 * tid] + ps[2 * tid + 1];
    const float q = pq[2 * tid] + pq[2 * tid + 1];
    const float m = s * (1.f / 1024.f);
    rowm[tid] = m;
    rowr[tid] = rsqrtf(q * (1.f / 1024.f) - m * m + 1e-5f);
  }
  __syncthreads();

  const int l = tid & 63;
  const int w = tid >> 6;
  const int wm = w >> 1, wn = w & 1;
  const int lane15 = l & 15, lgrp = l >> 4;
  f32x4 zero4 = {0.f, 0.f, 0.f, 0.f};
  f32x4 acc[4][4];
#pragma unroll
  for (int ri = 0; ri < 4; ++ri)
#pragma unroll
    for (int ci = 0; ci < 4; ++ci) acc[ri][ci] = zero4;

  for (int k0 = 0; k0 < 1024; k0 += 64) {
    __syncthreads();
#pragma unroll
    for (int i = 0; i < 4; ++i) {
      const int c = tid + i * 256;
      const int r = c >> 3, cc = c & 7;
      const int k = k0 + cc * 8;
      {
        const bf16x8 v = *(const bf16x8*)(araw + (brow + r) * 1024 + k);
        const float mm = rowm[r], rr = rowr[r];
        bf16x8 o;
#pragma unroll
        for (int e = 0; e < 8; ++e)
          o[e] = f2bf((bf2f(v[e]) - mm) * rr * lnw_s[k + e] + lnb_s[k + e]);
        *(bf16x8*)&As[r * 64 + cc * 8] = o;
      }
      {
        const float4* bp = (const float4*)(W2 + (bcol + r) * 1024 + k);
        const float4 v0 = bp[0], v1 = bp[1];
        bf16x8 o;
        o[0] = f2bf(v0.x); o[1] = f2bf(v0.y); o[2] = f2bf(v0.z); o[3] = f2bf(v0.w);
        o[4] = f2bf(v1.x); o[5] = f2bf(v1.y); o[6] = f2bf(v1.z); o[7] = f2bf(v1.w);
        *(bf16x8*)&Bs[r * 64 + cc * 8] = o;
      }
    }
    __syncthreads();
#pragma unroll
    for (int kk = 0; kk < 2; ++kk) {
      const int ko = kk * 32 + lgrp * 8;
      bf16x8 av[4], bv[4];
#pragma unroll
      for (int ri = 0; ri < 4; ++ri) av[ri] = *(const bf16x8*)&As[(wm * 64 + ri * 16 + lane15) * 64 + ko];
#pragma unroll
      for (int ci = 0; ci < 4; ++ci) bv[ci] = *(const bf16x8*)&Bs[(wn * 64 + ci * 16 + lane15) * 64 + ko];
#pragma unroll
      for (int ri = 0; ri < 4; ++ri)
#pragma unroll
        for (int ci = 0; ci < 4; ++ci) acc[ri][ci] = mfma16(av[ri], bv[ci], acc[ri][ci]);
    }
  }
#pragma unroll
  for (int ri = 0; ri < 4; ++ri)
#pragma unroll
    for (int ci = 0; ci < 4; ++ci)
#pragma unroll
      for (int i = 0; i < 4; ++i) {
        const long mrow = brow + wm * 64 + ri * 16 + lgrp * 4 + i;
        const long ncol = bcol + wn * 64 + ci * 16 + lane15;
        const int tq = (int)(mrow >> 4), b = (int)(mrow & 15);
        C[(size_t)b * TT * VOCAB + (size_t)tq * VOCAB + ncol] = acc[ri][ci][i] + b2[ncol];
      }
}

// ---------------- host launch ----------------
extern "C" void kernel_launch(void* const* d_in, const int* in_sizes, int n_in,
                              void* d_out, int out_size, void* d_ws, size_t ws_size,
                              hipStream_t stream) {
  const int* input = (const int*)d_in[0];
  const float* embd = (const float*)d_in[1];
  const float* Wih0 = (const float*)d_in[2];
  const float* Whh0 = (const float*)d_in[3];
  const float* bih0 = (const float*)d_in[4];
  const float* bhh0 = (const float*)d_in[5];
  const float* ln0w = (const float*)d_in[6];
  const float* ln0b = (const float*)d_in[7];
  const float* Wih1 = (const float*)d_in[8];
  const float* Whh1 = (const float*)d_in[9];
  const float* bih1 = (const float*)d_in[10];
  const float* bhh1 = (const float*)d_in[11];
  const float* ln1w = (const float*)d_in[12];
  const float* ln1b = (const float*)d_in[13];
  const float* W1 = (const float*)d_in[14];
  const float* b1 = (const float*)d_in[15];
  const float* ln2w = (const float*)d_in[16];
  const float* ln2b = (const float*)d_in[17];
  const float* W2 = (const float*)d_in[18];
  const float* b2 = (const float*)d_in[19];
  float* out = (float*)d_out;

  // ws (25.4 MB): rings + h1 history + araw + barrier.
  char* ws = (char*)d_ws;
  size_t off = 0;
  auto alloc = [&](size_t bytes) -> char* {
    char* p = ws + off;
    off = (off + bytes + 255) & ~(size_t)255;
    return p;
  };
  double* h0ring = (double*)alloc(2ull * 16 * 1024 * 8);
  double* h1ring = (double*)alloc(2ull * 16 * 1024 * 8);
  float* h1hist = (float*)alloc(4096ull * 1024 * 4);
  short* araw = (short*)alloc(4096ull * 1024 * 2);
  int* bar = (int*)alloc(256);

  hipMemsetAsync(bar, 0, 256, stream);

  // gi0 (100.7 MB f64) in d_out-as-scratch: fully consumed by k_recur; k_head
  // then overwrites every byte of d_out.
  double* gi0 = (double*)d_out;

  k_gi0<<<4096, 256, 0, stream>>>(input, embd, Wih0, bih0, gi0);

  SP A;
  A.Whh0 = Whh0; A.bhh0 = bhh0; A.ln0w = ln0w; A.ln0b = ln0b;
  A.Wih1 = Wih1; A.Whh1 = Whh1; A.bih1 = bih1; A.bhh1 = bhh1;
  A.ln1w = ln1w; A.ln1b = ln1b;
  A.gi0 = gi0; A.h0ring = h0ring; A.h1ring = h1ring; A.h1hist = h1hist;
  A.bar = bar;
  k_recur<<<NBLK, 512, 0, stream>>>(A);

  k_headpre<<<256, 512, 0, stream>>>(h1hist, ln1w, ln1b, W1, b1, araw);

  k_head<<<dim3(250, 32), 256, 0, stream>>>(araw, W2, ln2w, ln2b, b2, out);
}

// Round 15
// 15404.878 us; speedup vs baseline: 2.6037x; 1.0382x over previous
//
#include <hip/hip_runtime.h>
#include <stdint.h>
#include <math.h>

#define TT 256
#define VOCAB 32000
#define LN_EPS 1e-5
#define NBLK 256

typedef __attribute__((ext_vector_type(8))) short bf16x8;
typedef __attribute__((ext_vector_type(4))) float f32x4;

__device__ __forceinline__ float bf2f(short s) {
  return __uint_as_float(((uint32_t)(uint16_t)s) << 16);
}
__device__ __forceinline__ short f2bf(float f) {
  uint32_t u = __float_as_uint(f);
  u += 0x7fffu + ((u >> 16) & 1u);
  return (short)(u >> 16);
}
__device__ __forceinline__ f32x4 mfma16(bf16x8 a, bf16x8 b, f32x4 c) {
  return __builtin_amdgcn_mfma_f32_16x16x32_bf16(a, b, c, 0, 0, 0);
}

// coherent (L2-bypassing) h-ring access (r14-validated): relaxed agent atomics
// hit the coherent point -> cross-XCD visibility with NO cache-flush fences.
__device__ __forceinline__ double cload(const double* p) {
  return __hip_atomic_load(p, __ATOMIC_RELAXED, __HIP_MEMORY_SCOPE_AGENT);
}
__device__ __forceinline__ void cstore(double* p, double v) {
  __hip_atomic_store(p, v, __ATOMIC_RELAXED, __HIP_MEMORY_SCOPE_AGENT);
}

// ---------------- gi0 = embd[input] @ Wih0^T + bih0, f64, fully parallel ----------------
__global__ void k_gi0(const int* __restrict__ input, const float* __restrict__ embd,
                      const float* __restrict__ Wih0, const float* __restrict__ bih0,
                      double* __restrict__ gi0) {
  const int t = blockIdx.x >> 4;
  const int cg = blockIdx.x & 15;
  const int tid = threadIdx.x;
  __shared__ float xs[16][512];
  for (int idx = tid; idx < 16 * 512; idx += 256) {
    const int r = idx >> 9, j = idx & 511;
    const int tok = input[r * TT + t];
    xs[r][j] = embd[(size_t)tok * 512 + j];
  }
  __syncthreads();
  const int row = tid >> 4, ct = tid & 15;
  for (int i = 0; i < 12; ++i) {
    const int c = cg * 192 + ct + 16 * i;
    const float4* wp = (const float4*)(Wih0 + (size_t)c * 512);
    const float4* xp = (const float4*)&xs[row][0];
    double acc = 0.0;
#pragma unroll 8
    for (int j4 = 0; j4 < 128; ++j4) {
      const float4 w = wp[j4];
      const float4 x = xp[j4];
      acc = fma((double)x.x, (double)w.x, acc);
      acc = fma((double)x.y, (double)w.y, acc);
      acc = fma((double)x.z, (double)w.z, acc);
      acc = fma((double)x.w, (double)w.w, acc);
    }
    gi0[((size_t)t * 16 + row) * 3072 + c] = acc + (double)bih0[c];
  }
}

// ---------------- persistent recurrence: LDS weights + hierarchical barrier ----------------
struct SP {
  const float *Whh0, *bhh0, *ln0w, *ln0b;
  const float *Wih1, *Whh1, *bih1, *bhh1, *ln1w, *ln1b;
  const double* gi0;
  double *h0ring, *h1ring;  // [2][16][1024] f64 raw hidden states (coherent access)
  float* h1hist;            // [256*16][1024] f32 raw h1 history (plain stores)
  int* bar;                 // hierarchical barrier region (16 KB)
};

__device__ __forceinline__ void loadR(const double* __restrict__ hrow, const int l,
                                      double* __restrict__ a) {
#pragma unroll
  for (int jj = 0; jj < 8; ++jj) {
    a[jj*2]   = cload(hrow + jj * 128 + l * 2);
    a[jj*2+1] = cload(hrow + jj * 128 + l * 2 + 1);
  }
}

// stats+normalize in the same accumulation order as r13/r14 (bit-identical).
__device__ __forceinline__ void statsLN(double* __restrict__ a,
                                        const float* __restrict__ lnw,
                                        const float* __restrict__ lnb,
                                        const int l, double& m_out, double& rs_out) {
  double s = 0.0, q = 0.0;
#pragma unroll
  for (int jj = 0; jj < 8; ++jj) {
    const double x0 = a[jj*2], x1 = a[jj*2+1];
    s += x0 + x1; q += x0*x0 + x1*x1;
  }
#pragma unroll
  for (int mk = 1; mk <= 32; mk <<= 1) { s += __shfl_xor(s, mk); q += __shfl_xor(q, mk); }
  const double m = s * (1.0 / 1024.0);
  const double rs = 1.0 / sqrt(q * (1.0 / 1024.0) - m * m + LN_EPS);
#pragma unroll
  for (int jj = 0; jj < 8; ++jj) {
    const float2 lw = *(const float2*)(lnw + jj * 128 + l * 2);
    const float2 lb = *(const float2*)(lnb + jj * 128 + l * 2);
    a[jj*2]   = (a[jj*2]   - m) * rs * (double)lw.x + (double)lb.x;
    a[jj*2+1] = (a[jj*2+1] - m) * rs * (double)lw.y + (double)lb.y;
  }
  m_out = m; rs_out = rs;
}

__launch_bounds__(512, 1)
__global__ void k_recur(SP A) {
  __shared__ float wlds[36][1024];   // 147456 B weight slice (f32), resident all phases
  __shared__ double sPre[36][16];    // dot sums [weight-row][batch-row]
  __shared__ double sM0[16], sR0[16], sM1[16], sR1[16];
  const int tid = threadIdx.x;
  const int w = tid >> 6;  // wave 0..7 -> batch rows 2w, 2w+1
  const int l = tid & 63;
  const int bid = blockIdx.x;
  const int col0 = bid * 4;

  // ---- one-time: weight slice -> LDS. j<12: Whh0; 12..23: Wih1; 24..35: Whh1
  for (int idx = tid; idx < 36 * 1024; idx += 512) {
    const int j = idx >> 10, k = idx & 1023;
    const int jj = (j < 12) ? j : (j < 24 ? j - 12 : j - 24);
    const int g = jj % 3, ci = jj / 3;
    const float* W = (j < 12) ? A.Whh0 : (j < 24 ? A.Wih1 : A.Whh1);
    wlds[j][k] = W[(size_t)(g * 1024 + col0 + ci) * 1024 + k];
  }
  __syncthreads();

  for (int p = 0; p <= TT; ++p) {
    const bool doL0 = (p < TT);
    const int t1 = p - 1;
    double a0a[16], a0b[16], a1a[16], a1b[16];

    if (p >= 1) {
      // ---- issue ALL coherent loads up front (a1 latency hides under a0 dots) ----
      const double* base0 = A.h0ring + (size_t)((p - 1) & 1) * 16384;
      loadR(base0 + (2 * w) * 1024, l, a0a);
      loadR(base0 + (2 * w + 1) * 1024, l, a0b);
      if (t1 > 0) {
        const double* base1 = A.h1ring + (size_t)((t1 - 1) & 1) * 16384;
        loadR(base1 + (2 * w) * 1024, l, a1a);
        loadR(base1 + (2 * w + 1) * 1024, l, a1b);
      }
      double ma, ra, mb, rb;
      statsLN(a0a, A.ln0w, A.ln0b, l, ma, ra);
      statsLN(a0b, A.ln0w, A.ln0b, l, mb, rb);
      if (l == 0) { sM0[2*w] = ma; sR0[2*w] = ra; sM0[2*w+1] = mb; sR0[2*w+1] = rb; }
      const int j0 = doL0 ? 0 : 12;
      for (int j = j0; j < 24; ++j) {
        double c0 = 0.0, c1 = 0.0;
#pragma unroll
        for (int jj = 0; jj < 8; ++jj) {
          const float2 wv = *(const float2*)&wlds[j][jj * 128 + l * 2];
          const double wx = (double)wv.x, wy = (double)wv.y;
          c0 = fma(wx, a0a[jj*2], c0); c0 = fma(wy, a0a[jj*2+1], c0);
          c1 = fma(wx, a0b[jj*2], c1); c1 = fma(wy, a0b[jj*2+1], c1);
        }
#pragma unroll
        for (int mk = 1; mk <= 32; mk <<= 1) { c0 += __shfl_xor(c0, mk); c1 += __shfl_xor(c1, mk); }
        if (l == 0) { sPre[j][2*w] = c0; sPre[j][2*w+1] = c1; }
      }
      if (t1 > 0) {
        statsLN(a1a, A.ln1w, A.ln1b, l, ma, ra);
        statsLN(a1b, A.ln1w, A.ln1b, l, mb, rb);
        if (l == 0) { sM1[2*w] = ma; sR1[2*w] = ra; sM1[2*w+1] = mb; sR1[2*w+1] = rb; }
        for (int j = 24; j < 36; ++j) {
          double c0 = 0.0, c1 = 0.0;
#pragma unroll
          for (int jj = 0; jj < 8; ++jj) {
            const float2 wv = *(const float2*)&wlds[j][jj * 128 + l * 2];
            const double wx = (double)wv.x, wy = (double)wv.y;
            c0 = fma(wx, a1a[jj*2], c0); c0 = fma(wy, a1a[jj*2+1], c0);
            c1 = fma(wx, a1b[jj*2], c1); c1 = fma(wy, a1b[jj*2+1], c1);
          }
#pragma unroll
          for (int mk = 1; mk <= 32; mk <<= 1) { c0 += __shfl_xor(c0, mk); c1 += __shfl_xor(c1, mk); }
          if (l == 0) { sPre[j][2*w] = c0; sPre[j][2*w+1] = c1; }
        }
      }
    }
    __syncthreads();

    // ---- gates: L0 on threads 0..63, L1 on threads 64..127 ----
    if (doL0 && tid < 64) {
      const int r = tid >> 2, ci = tid & 3;
      const int c = col0 + ci;
      const int t0 = p;
      double ghr, ghz, ghn, hprev;
      if (t0 > 0) {
        ghr = sPre[ci*3+0][r] + (double)A.bhh0[c];
        ghz = sPre[ci*3+1][r] + (double)A.bhh0[c + 1024];
        ghn = sPre[ci*3+2][r] + (double)A.bhh0[c + 2048];
        const double praw = cload(A.h0ring + (size_t)((t0 - 1) & 1) * 16384 + r * 1024 + c);
        hprev = (praw - sM0[r]) * sR0[r] * (double)A.ln0w[c] + (double)A.ln0b[c];
      } else {
        ghr = (double)A.bhh0[c]; ghz = (double)A.bhh0[c + 1024]; ghn = (double)A.bhh0[c + 2048];
        hprev = 0.0;
      }
      const double* gp = A.gi0 + ((size_t)t0 * 16 + r) * 3072 + c;
      const double gir = gp[0], giz = gp[1024], gin = gp[2048];
      const double rg = 1.0 / (1.0 + exp(-(gir + ghr)));
      const double zg = 1.0 / (1.0 + exp(-(giz + ghz)));
      const double ng = tanh(gin + rg * ghn);
      cstore(A.h0ring + (size_t)(t0 & 1) * 16384 + r * 1024 + c, (1.0 - zg) * ng + zg * hprev);
    }
    if (t1 >= 0 && tid >= 64 && tid < 128) {
      const int r = (tid - 64) >> 2, ci = (tid - 64) & 3;
      const int c = col0 + ci;
      const double gir = sPre[12+ci*3+0][r] + (double)A.bih1[c];
      const double giz = sPre[12+ci*3+1][r] + (double)A.bih1[c + 1024];
      const double gin = sPre[12+ci*3+2][r] + (double)A.bih1[c + 2048];
      double ghr, ghz, ghn, hprev;
      if (t1 > 0) {
        ghr = sPre[24+ci*3+0][r] + (double)A.bhh1[c];
        ghz = sPre[24+ci*3+1][r] + (double)A.bhh1[c + 1024];
        ghn = sPre[24+ci*3+2][r] + (double)A.bhh1[c + 2048];
        const double praw = cload(A.h1ring + (size_t)((t1 - 1) & 1) * 16384 + r * 1024 + c);
        hprev = (praw - sM1[r]) * sR1[r] * (double)A.ln1w[c] + (double)A.ln1b[c];
      } else {
        ghr = (double)A.bhh1[c]; ghz = (double)A.bhh1[c + 1024]; ghn = (double)A.bhh1[c + 2048];
        hprev = 0.0;
      }
      const double rg = 1.0 / (1.0 + exp(-(gir + ghr)));
      const double zg = 1.0 / (1.0 + exp(-(giz + ghz)));
      const double ng = tanh(gin + rg * ghn);
      const double hnew = (1.0 - zg) * ng + zg * hprev;
      cstore(A.h1ring + (size_t)(t1 & 1) * 16384 + r * 1024 + c, hnew);
      A.h1hist[((size_t)t1 * 16 + r) * 1024 + c] = (float)hnew;
    }

    // ---------- hierarchical fence-free barrier ----------
    // r14's flat barrier: 256 RMWs + 255 pollers on ONE L3 line every 53ns.
    // Tree: 32 group counters (128B apart), group-last (unique fetch_add return)
    // arrives at global (32 adds, 32 pollers), then releases its group flag
    // (7 pollers/line). __syncthreads before arrival drains coherent stores.
    __syncthreads();
    if (tid == 0) {
      const int g = bid >> 3;
      int* grpC = A.bar + g * 32;          // 128B stride
      int* glob = A.bar + 32 * 32;
      int* rel  = A.bar + 33 * 32 + g * 32;
      const int my = __hip_atomic_fetch_add(grpC, 1, __ATOMIC_RELAXED, __HIP_MEMORY_SCOPE_AGENT);
      if (my == 8 * (p + 1) - 1) {
        __hip_atomic_fetch_add(glob, 1, __ATOMIC_RELAXED, __HIP_MEMORY_SCOPE_AGENT);
        while (__hip_atomic_load(glob, __ATOMIC_RELAXED, __HIP_MEMORY_SCOPE_AGENT) < 32 * (p + 1)) {
          __builtin_amdgcn_s_sleep(2);
        }
        __hip_atomic_store(rel, p + 1, __ATOMIC_RELAXED, __HIP_MEMORY_SCOPE_AGENT);
      } else {
        while (__hip_atomic_load(rel, __ATOMIC_RELAXED, __HIP_MEMORY_SCOPE_AGENT) < p + 1) {
          __builtin_amdgcn_s_sleep(8);
        }
      }
    }
    __syncthreads();
  }
}

// ---------------- batched head pre-proj (byte-identical to rounds 7-14) ----------------
__launch_bounds__(512, 2)
__global__ void k_headpre(const float* __restrict__ h1hist, const float* __restrict__ ln1w,
                          const float* __restrict__ ln1b, const float* __restrict__ W1,
                          const float* __restrict__ b1, short* __restrict__ araw) {
  const int tid = threadIdx.x;
  const int row = tid >> 5, ks = tid & 31;
  const size_t m = (size_t)blockIdx.x * 16 + row;
  const float* hp = h1hist + m * 1024;
  float a[32];
  float s = 0.f, q = 0.f;
#pragma unroll
  for (int g = 0; g < 8; ++g) {
    const float4 v = *(const float4*)(hp + g * 128 + ks * 4);
    a[g*4+0] = v.x; a[g*4+1] = v.y; a[g*4+2] = v.z; a[g*4+3] = v.w;
    s += v.x + v.y + v.z + v.w;
    q += v.x * v.x + v.y * v.y + v.z * v.z + v.w * v.w;
  }
#pragma unroll
  for (int mk = 1; mk <= 16; mk <<= 1) { s += __shfl_xor(s, mk); q += __shfl_xor(q, mk); }
  const float mn = s * (1.f / 1024.f);
  const float rs = rsqrtf(q * (1.f / 1024.f) - mn * mn + 1e-5f);
#pragma unroll
  for (int g = 0; g < 8; ++g) {
    const float4 lw = *(const float4*)(ln1w + g * 128 + ks * 4);
    const float4 lb = *(const float4*)(ln1b + g * 128 + ks * 4);
    a[g*4+0] = (a[g*4+0] - mn) * rs * lw.x + lb.x;
    a[g*4+1] = (a[g*4+1] - mn) * rs * lw.y + lb.y;
    a[g*4+2] = (a[g*4+2] - mn) * rs * lw.z + lb.z;
    a[g*4+3] = (a[g*4+3] - mn) * rs * lw.w + lb.w;
  }
  for (int c = 0; c < 1024; ++c) {
    const float4* wp = (const float4*)(W1 + (size_t)c * 1024);
    float acc = 0.f;
#pragma unroll
    for (int g = 0; g < 8; ++g) {
      const float4 w = wp[g * 32 + ks];
      acc = fmaf(a[g*4+0], w.x, acc); acc = fmaf(a[g*4+1], w.y, acc);
      acc = fmaf(a[g*4+2], w.z, acc); acc = fmaf(a[g*4+3], w.w, acc);
    }
#pragma unroll
    for (int mk = 1; mk <= 16; mk <<= 1) acc += __shfl_xor(acc, mk);
    if (ks == 0) {
      const float y = acc + b1[c];
      araw[m * 1024 + c] = f2bf(y > 0.f ? y : 0.01f * y);
    }
  }
}

// ---------------- W2 -> bf16 (optional, ws-gated) ----------------
__global__ void k_w2q(const float* __restrict__ W2, short* __restrict__ W2q) {
  const int n = 32000 * 1024;
  for (int i = blockIdx.x * blockDim.x + threadIdx.x; i < n; i += gridDim.x * blockDim.x)
    W2q[i] = f2bf(W2[i]);
}

// ---------------- head GEMM. BW2=0: B from f32 W2 (rounds 6-14 path);
// BW2=1: B pre-quantized bf16 (identical values via same f2bf). ----------------
template <int BW2>
__global__ void k_head(const short* __restrict__ araw, const void* __restrict__ Bsrc,
                       const float* __restrict__ ln2w, const float* __restrict__ ln2b,
                       const float* __restrict__ b2, float* __restrict__ C) {
  __shared__ __align__(16) short As[128 * 64];
  __shared__ __align__(16) short Bs[128 * 64];
  __shared__ float rowm[128], rowr[128];
  __shared__ float lnw_s[1024], lnb_s[1024];
  __shared__ float ps[256], pq[256];
  const int tid = threadIdx.x;
  const long brow = (long)blockIdx.y * 128;
  const long bcol = (long)blockIdx.x * 128;

  for (int i = tid; i < 1024; i += 256) { lnw_s[i] = ln2w[i]; lnb_s[i] = ln2b[i]; }
  {
    const int r2 = tid >> 1, hf = tid & 1;
    const short* ap = araw + (brow + r2) * 1024 + hf * 512;
    float s = 0.f, q = 0.f;
    for (int j = 0; j < 512; j += 8) {
      const bf16x8 v = *(const bf16x8*)(ap + j);
#pragma unroll
      for (int e = 0; e < 8; ++e) { const float x = bf2f(v[e]); s += x; q += x * x; }
    }
    ps[tid] = s; pq[tid] = q;
  }
  __syncthreads();
  if (tid < 128) {
    const float s = ps[2 * tid] + ps[2 * tid + 1];
    const float q = pq[2 * tid] + pq[2 * tid + 1];
    const float m = s * (1.f / 1024.f);
    rowm[tid] = m;
    rowr[tid] = rsqrtf(q * (1.f / 1024.f) - m * m + 1e-5f);
  }
  __syncthreads();

  const int l = tid & 63;
  const int w = tid >> 6;
  const int wm = w >> 1, wn = w & 1;
  const int lane15 = l & 15, lgrp = l >> 4;
  f32x4 zero4 = {0.f, 0.f, 0.f, 0.f};
  f32x4 acc[4][4];
#pragma unroll
  for (int ri = 0; ri < 4; ++ri)
#pragma unroll
    for (int ci = 0; ci < 4; ++ci) acc[ri][ci] = zero4;

  for (int k0 = 0; k0 < 1024; k0 += 64) {
    __syncthreads();
#pragma unroll
    for (int i = 0; i < 4; ++i) {
      const int c = tid + i * 256;
      const int r = c >> 3, cc = c & 7;
      const int k = k0 + cc * 8;
      {
        const bf16x8 v = *(const bf16x8*)(araw + (brow + r) * 1024 + k);
        const float mm = rowm[r], rr = rowr[r];
        bf16x8 o;
#pragma unroll
        for (int e = 0; e < 8; ++e)
          o[e] = f2bf((bf2f(v[e]) - mm) * rr * lnw_s[k + e] + lnb_s[k + e]);
        *(bf16x8*)&As[r * 64 + cc * 8] = o;
      }
      if (BW2) {
        const short* bq = (const short*)Bsrc;
        *(bf16x8*)&Bs[r * 64 + cc * 8] = *(const bf16x8*)&bq[(bcol + r) * 1024 + k];
      } else {
        const float* bw = (const float*)Bsrc;
        const float4* bp = (const float4*)(bw + (bcol + r) * 1024 + k);
        const float4 v0 = bp[0], v1 = bp[1];
        bf16x8 o;
        o[0] = f2bf(v0.x); o[1] = f2bf(v0.y); o[2] = f2bf(v0.z); o[3] = f2bf(v0.w);
        o[4] = f2bf(v1.x); o[5] = f2bf(v1.y); o[6] = f2bf(v1.z); o[7] = f2bf(v1.w);
        *(bf16x8*)&Bs[r * 64 + cc * 8] = o;
      }
    }
    __syncthreads();
#pragma unroll
    for (int kk = 0; kk < 2; ++kk) {
      const int ko = kk * 32 + lgrp * 8;
      bf16x8 av[4], bv[4];
#pragma unroll
      for (int ri = 0; ri < 4; ++ri) av[ri] = *(const bf16x8*)&As[(wm * 64 + ri * 16 + lane15) * 64 + ko];
#pragma unroll
      for (int ci = 0; ci < 4; ++ci) bv[ci] = *(const bf16x8*)&Bs[(wn * 64 + ci * 16 + lane15) * 64 + ko];
#pragma unroll
      for (int ri = 0; ri < 4; ++ri)
#pragma unroll
        for (int ci = 0; ci < 4; ++ci) acc[ri][ci] = mfma16(av[ri], bv[ci], acc[ri][ci]);
    }
  }
#pragma unroll
  for (int ri = 0; ri < 4; ++ri)
#pragma unroll
    for (int ci = 0; ci < 4; ++ci)
#pragma unroll
      for (int i = 0; i < 4; ++i) {
        const long mrow = brow + wm * 64 + ri * 16 + lgrp * 4 + i;
        const long ncol = bcol + wn * 64 + ci * 16 + lane15;
        const int tq = (int)(mrow >> 4), b = (int)(mrow & 15);
        C[(size_t)b * TT * VOCAB + (size_t)tq * VOCAB + ncol] = acc[ri][ci][i] + b2[ncol];
      }
}

// ---------------- host launch ----------------
extern "C" void kernel_launch(void* const* d_in, const int* in_sizes, int n_in,
                              void* d_out, int out_size, void* d_ws, size_t ws_size,
                              hipStream_t stream) {
  const int* input = (const int*)d_in[0];
  const float* embd = (const float*)d_in[1];
  const float* Wih0 = (const float*)d_in[2];
  const float* Whh0 = (const float*)d_in[3];
  const float* bih0 = (const float*)d_in[4];
  const float* bhh0 = (const float*)d_in[5];
  const float* ln0w = (const float*)d_in[6];
  const float* ln0b = (const float*)d_in[7];
  const float* Wih1 = (const float*)d_in[8];
  const float* Whh1 = (const float*)d_in[9];
  const float* bih1 = (const float*)d_in[10];
  const float* bhh1 = (const float*)d_in[11];
  const float* ln1w = (const float*)d_in[12];
  const float* ln1b = (const float*)d_in[13];
  const float* W1 = (const float*)d_in[14];
  const float* b1 = (const float*)d_in[15];
  const float* ln2w = (const float*)d_in[16];
  const float* ln2b = (const float*)d_in[17];
  const float* W2 = (const float*)d_in[18];
  const float* b2 = (const float*)d_in[19];
  float* out = (float*)d_out;

  char* ws = (char*)d_ws;
  size_t off = 0;
  auto alloc = [&](size_t bytes) -> char* {
    char* p = ws + off;
    off = (off + bytes + 255) & ~(size_t)255;
    return p;
  };
  double* h0ring = (double*)alloc(2ull * 16 * 1024 * 8);
  double* h1ring = (double*)alloc(2ull * 16 * 1024 * 8);
  float* h1hist = (float*)alloc(4096ull * 1024 * 4);
  short* araw = (short*)alloc(4096ull * 1024 * 2);
  int* bar = (int*)alloc(16384);
  const size_t base_need = off;
  short* W2q = (short*)alloc(32000ull * 1024 * 2);
  const bool useW2q = (ws_size >= off);  // 64MB extra; fall back if ws too small
  (void)base_need;

  hipMemsetAsync(bar, 0, 16384, stream);

  // gi0 (100.7 MB f64) in d_out-as-scratch: fully consumed by k_recur; k_head
  // then overwrites every byte of d_out.
  double* gi0 = (double*)d_out;

  k_gi0<<<4096, 256, 0, stream>>>(input, embd, Wih0, bih0, gi0);

  SP A;
  A.Whh0 = Whh0; A.bhh0 = bhh0; A.ln0w = ln0w; A.ln0b = ln0b;
  A.Wih1 = Wih1; A.Whh1 = Whh1; A.bih1 = bih1; A.bhh1 = bhh1;
  A.ln1w = ln1w; A.ln1b = ln1b;
  A.gi0 = gi0; A.h0ring = h0ring; A.h1ring = h1ring; A.h1hist = h1hist;
  A.bar = bar;
  k_recur<<<NBLK, 512, 0, stream>>>(A);

  k_headpre<<<256, 512, 0, stream>>>(h1hist, ln1w, ln1b, W1, b1, araw);

  if (useW2q) {
    k_w2q<<<2048, 256, 0, stream>>>(W2, W2q);
    k_head<1><<<dim3(250, 32), 256, 0, stream>>>(araw, W2q, ln2w, ln2b, b2, out);
  } else {
    k_head<0><<<dim3(250, 32), 256, 0, stream>>>(araw, W2, ln2w, ln2b, b2, out);
  }
}

// Round 16
// 15016.238 us; speedup vs baseline: 2.6710x; 1.0259x over previous
//
#include <hip/hip_runtime.h>
#include <stdint.h>
#include <math.h>

#define TT 256
#define VOCAB 32000
#define LN_EPS 1e-5
#define NBLK 256

typedef __attribute__((ext_vector_type(8))) short bf16x8;
typedef __attribute__((ext_vector_type(4))) float f32x4;

__device__ __forceinline__ float bf2f(short s) {
  return __uint_as_float(((uint32_t)(uint16_t)s) << 16);
}
__device__ __forceinline__ short f2bf(float f) {
  uint32_t u = __float_as_uint(f);
  u += 0x7fffu + ((u >> 16) & 1u);
  return (short)(u >> 16);
}
__device__ __forceinline__ f32x4 mfma16(bf16x8 a, bf16x8 b, f32x4 c) {
  return __builtin_amdgcn_mfma_f32_16x16x32_bf16(a, b, c, 0, 0, 0);
}

// coherent store: relaxed agent atomic -> coherent point (L3); no fences needed.
__device__ __forceinline__ void cstore(double* p, double v) {
  __hip_atomic_store(p, v, __ATOMIC_RELAXED, __HIP_MEMORY_SCOPE_AGENT);
}

// ---------------- gi0 = embd[input] @ Wih0^T + bih0, f64, fully parallel ----------------
__global__ void k_gi0(const int* __restrict__ input, const float* __restrict__ embd,
                      const float* __restrict__ Wih0, const float* __restrict__ bih0,
                      double* __restrict__ gi0) {
  const int t = blockIdx.x >> 4;
  const int cg = blockIdx.x & 15;
  const int tid = threadIdx.x;
  __shared__ float xs[16][512];
  for (int idx = tid; idx < 16 * 512; idx += 256) {
    const int r = idx >> 9, j = idx & 511;
    const int tok = input[r * TT + t];
    xs[r][j] = embd[(size_t)tok * 512 + j];
  }
  __syncthreads();
  const int row = tid >> 4, ct = tid & 15;
  for (int i = 0; i < 12; ++i) {
    const int c = cg * 192 + ct + 16 * i;
    const float4* wp = (const float4*)(Wih0 + (size_t)c * 512);
    const float4* xp = (const float4*)&xs[row][0];
    double acc = 0.0;
#pragma unroll 8
    for (int j4 = 0; j4 < 128; ++j4) {
      const float4 w = wp[j4];
      const float4 x = xp[j4];
      acc = fma((double)x.x, (double)w.x, acc);
      acc = fma((double)x.y, (double)w.y, acc);
      acc = fma((double)x.z, (double)w.z, acc);
      acc = fma((double)x.w, (double)w.w, acc);
    }
    gi0[((size_t)t * 16 + row) * 3072 + c] = acc + (double)bih0[c];
  }
}

// ---------------- persistent recurrence: LDS weights + TT-deep h history ----------------
// r15 lesson: coherent ATOMIC loads = 8.4M 8B transactions/phase at the
// coherent point (~20us/phase). Fix: h state kept in TT-deep histories whose
// addresses are NEVER reused within the dispatch -> readers use PLAIN wide
// loads (first touch per address; no stale L2 line can exist; per-dispatch L2
// invalidate covers cross-replay staleness). Writers stay coherent cstore
// (0.5MB/phase chip-wide). Math bit-identical to r13-15.
struct SP {
  const float *Whh0, *bhh0, *ln0w, *ln0b;
  const float *Wih1, *Whh1, *bih1, *bhh1, *ln1w, *ln1b;
  const double* gi0;
  double *h0hist, *h1hist64;  // [TT][16][1024] f64 (d_out scratch)
  float* h1hist;              // [256*16][1024] f32 (ws, for k_headpre)
  int* bar;                   // hierarchical barrier region (16 KB)
};

__device__ __forceinline__ void loadP(const double* __restrict__ hrow, const int l,
                                      double* __restrict__ a) {
#pragma unroll
  for (int jj = 0; jj < 8; ++jj) {
    const double2 x = *(const double2*)(hrow + jj * 128 + l * 2);
    a[jj*2] = x.x; a[jj*2+1] = x.y;
  }
}

// stats+normalize, accumulation order bit-identical to r13-15.
__device__ __forceinline__ void statsLN(double* __restrict__ a,
                                        const float* __restrict__ lnw,
                                        const float* __restrict__ lnb,
                                        const int l, double& m_out, double& rs_out) {
  double s = 0.0, q = 0.0;
#pragma unroll
  for (int jj = 0; jj < 8; ++jj) {
    const double x0 = a[jj*2], x1 = a[jj*2+1];
    s += x0 + x1; q += x0*x0 + x1*x1;
  }
#pragma unroll
  for (int mk = 1; mk <= 32; mk <<= 1) { s += __shfl_xor(s, mk); q += __shfl_xor(q, mk); }
  const double m = s * (1.0 / 1024.0);
  const double rs = 1.0 / sqrt(q * (1.0 / 1024.0) - m * m + LN_EPS);
#pragma unroll
  for (int jj = 0; jj < 8; ++jj) {
    const float2 lw = *(const float2*)(lnw + jj * 128 + l * 2);
    const float2 lb = *(const float2*)(lnb + jj * 128 + l * 2);
    a[jj*2]   = (a[jj*2]   - m) * rs * (double)lw.x + (double)lb.x;
    a[jj*2+1] = (a[jj*2+1] - m) * rs * (double)lw.y + (double)lb.y;
  }
  m_out = m; rs_out = rs;
}

__launch_bounds__(512, 1)
__global__ void k_recur(SP A) {
  __shared__ float wlds[36][1024];   // 147456 B weight slice (f32), resident all phases
  __shared__ double sPre[36][16];    // dot sums [weight-row][batch-row]
  __shared__ double sM0[16], sR0[16], sM1[16], sR1[16];
  const int tid = threadIdx.x;
  const int w = tid >> 6;  // wave 0..7 -> batch rows 2w, 2w+1
  const int l = tid & 63;
  const int bid = blockIdx.x;
  const int col0 = bid * 4;

  // ---- one-time: weight slice -> LDS. j<12: Whh0; 12..23: Wih1; 24..35: Whh1
  for (int idx = tid; idx < 36 * 1024; idx += 512) {
    const int j = idx >> 10, k = idx & 1023;
    const int jj = (j < 12) ? j : (j < 24 ? j - 12 : j - 24);
    const int g = jj % 3, ci = jj / 3;
    const float* W = (j < 12) ? A.Whh0 : (j < 24 ? A.Wih1 : A.Whh1);
    wlds[j][k] = W[(size_t)(g * 1024 + col0 + ci) * 1024 + k];
  }
  __syncthreads();

  for (int p = 0; p <= TT; ++p) {
    const bool doL0 = (p < TT);
    const int t1 = p - 1;
    double a0a[16], a0b[16], a1a[16], a1b[16];

    if (p >= 1) {
      // ---- plain wide loads from never-reused addresses (line-granular L3) ----
      const double* base0 = A.h0hist + (size_t)(p - 1) * 16384;
      loadP(base0 + (2 * w) * 1024, l, a0a);
      loadP(base0 + (2 * w + 1) * 1024, l, a0b);
      if (t1 > 0) {
        const double* base1 = A.h1hist64 + (size_t)(t1 - 1) * 16384;
        loadP(base1 + (2 * w) * 1024, l, a1a);
        loadP(base1 + (2 * w + 1) * 1024, l, a1b);
      }
      double ma, ra, mb, rb;
      statsLN(a0a, A.ln0w, A.ln0b, l, ma, ra);
      statsLN(a0b, A.ln0w, A.ln0b, l, mb, rb);
      if (l == 0) { sM0[2*w] = ma; sR0[2*w] = ra; sM0[2*w+1] = mb; sR0[2*w+1] = rb; }
      const int j0 = doL0 ? 0 : 12;
      for (int j = j0; j < 24; ++j) {
        double c0 = 0.0, c1 = 0.0;
#pragma unroll
        for (int jj = 0; jj < 8; ++jj) {
          const float2 wv = *(const float2*)&wlds[j][jj * 128 + l * 2];
          const double wx = (double)wv.x, wy = (double)wv.y;
          c0 = fma(wx, a0a[jj*2], c0); c0 = fma(wy, a0a[jj*2+1], c0);
          c1 = fma(wx, a0b[jj*2], c1); c1 = fma(wy, a0b[jj*2+1], c1);
        }
#pragma unroll
        for (int mk = 1; mk <= 32; mk <<= 1) { c0 += __shfl_xor(c0, mk); c1 += __shfl_xor(c1, mk); }
        if (l == 0) { sPre[j][2*w] = c0; sPre[j][2*w+1] = c1; }
      }
      if (t1 > 0) {
        statsLN(a1a, A.ln1w, A.ln1b, l, ma, ra);
        statsLN(a1b, A.ln1w, A.ln1b, l, mb, rb);
        if (l == 0) { sM1[2*w] = ma; sR1[2*w] = ra; sM1[2*w+1] = mb; sR1[2*w+1] = rb; }
        for (int j = 24; j < 36; ++j) {
          double c0 = 0.0, c1 = 0.0;
#pragma unroll
          for (int jj = 0; jj < 8; ++jj) {
            const float2 wv = *(const float2*)&wlds[j][jj * 128 + l * 2];
            const double wx = (double)wv.x, wy = (double)wv.y;
            c0 = fma(wx, a1a[jj*2], c0); c0 = fma(wy, a1a[jj*2+1], c0);
            c1 = fma(wx, a1b[jj*2], c1); c1 = fma(wy, a1b[jj*2+1], c1);
          }
#pragma unroll
          for (int mk = 1; mk <= 32; mk <<= 1) { c0 += __shfl_xor(c0, mk); c1 += __shfl_xor(c1, mk); }
          if (l == 0) { sPre[j][2*w] = c0; sPre[j][2*w+1] = c1; }
        }
      }
    }
    __syncthreads();

    // ---- gates: L0 on threads 0..63, L1 on threads 64..127 ----
    if (doL0 && tid < 64) {
      const int r = tid >> 2, ci = tid & 3;
      const int c = col0 + ci;
      const int t0 = p;
      double ghr, ghz, ghn, hprev;
      if (t0 > 0) {
        ghr = sPre[ci*3+0][r] + (double)A.bhh0[c];
        ghz = sPre[ci*3+1][r] + (double)A.bhh0[c + 1024];
        ghn = sPre[ci*3+2][r] + (double)A.bhh0[c + 2048];
        const double praw = A.h0hist[(size_t)(t0 - 1) * 16384 + r * 1024 + c];  // line cached this phase
        hprev = (praw - sM0[r]) * sR0[r] * (double)A.ln0w[c] + (double)A.ln0b[c];
      } else {
        ghr = (double)A.bhh0[c]; ghz = (double)A.bhh0[c + 1024]; ghn = (double)A.bhh0[c + 2048];
        hprev = 0.0;
      }
      const double* gp = A.gi0 + ((size_t)t0 * 16 + r) * 3072 + c;
      const double gir = gp[0], giz = gp[1024], gin = gp[2048];
      const double rg = 1.0 / (1.0 + exp(-(gir + ghr)));
      const double zg = 1.0 / (1.0 + exp(-(giz + ghz)));
      const double ng = tanh(gin + rg * ghn);
      cstore(A.h0hist + (size_t)t0 * 16384 + r * 1024 + c, (1.0 - zg) * ng + zg * hprev);
    }
    if (t1 >= 0 && tid >= 64 && tid < 128) {
      const int r = (tid - 64) >> 2, ci = (tid - 64) & 3;
      const int c = col0 + ci;
      const double gir = sPre[12+ci*3+0][r] + (double)A.bih1[c];
      const double giz = sPre[12+ci*3+1][r] + (double)A.bih1[c + 1024];
      const double gin = sPre[12+ci*3+2][r] + (double)A.bih1[c + 2048];
      double ghr, ghz, ghn, hprev;
      if (t1 > 0) {
        ghr = sPre[24+ci*3+0][r] + (double)A.bhh1[c];
        ghz = sPre[24+ci*3+1][r] + (double)A.bhh1[c + 1024];
        ghn = sPre[24+ci*3+2][r] + (double)A.bhh1[c + 2048];
        const double praw = A.h1hist64[(size_t)(t1 - 1) * 16384 + r * 1024 + c];
        hprev = (praw - sM1[r]) * sR1[r] * (double)A.ln1w[c] + (double)A.ln1b[c];
      } else {
        ghr = (double)A.bhh1[c]; ghz = (double)A.bhh1[c + 1024]; ghn = (double)A.bhh1[c + 2048];
        hprev = 0.0;
      }
      const double rg = 1.0 / (1.0 + exp(-(gir + ghr)));
      const double zg = 1.0 / (1.0 + exp(-(giz + ghz)));
      const double ng = tanh(gin + rg * ghn);
      const double hnew = (1.0 - zg) * ng + zg * hprev;
      cstore(A.h1hist64 + (size_t)t1 * 16384 + r * 1024 + c, hnew);
      A.h1hist[((size_t)t1 * 16 + r) * 1024 + c] = (float)hnew;
    }

    // ---------- hierarchical fence-free barrier (r15) ----------
    __syncthreads();
    if (tid == 0) {
      const int g = bid >> 3;
      int* grpC = A.bar + g * 32;
      int* glob = A.bar + 32 * 32;
      int* rel  = A.bar + 33 * 32 + g * 32;
      const int my = __hip_atomic_fetch_add(grpC, 1, __ATOMIC_RELAXED, __HIP_MEMORY_SCOPE_AGENT);
      if (my == 8 * (p + 1) - 1) {
        __hip_atomic_fetch_add(glob, 1, __ATOMIC_RELAXED, __HIP_MEMORY_SCOPE_AGENT);
        while (__hip_atomic_load(glob, __ATOMIC_RELAXED, __HIP_MEMORY_SCOPE_AGENT) < 32 * (p + 1)) {
          __builtin_amdgcn_s_sleep(2);
        }
        __hip_atomic_store(rel, p + 1, __ATOMIC_RELAXED, __HIP_MEMORY_SCOPE_AGENT);
      } else {
        while (__hip_atomic_load(rel, __ATOMIC_RELAXED, __HIP_MEMORY_SCOPE_AGENT) < p + 1) {
          __builtin_amdgcn_s_sleep(8);
        }
      }
    }
    __syncthreads();
  }
}

// ---------------- batched head pre-proj (byte-identical to rounds 7-15) ----------------
__launch_bounds__(512, 2)
__global__ void k_headpre(const float* __restrict__ h1hist, const float* __restrict__ ln1w,
                          const float* __restrict__ ln1b, const float* __restrict__ W1,
                          const float* __restrict__ b1, short* __restrict__ araw) {
  const int tid = threadIdx.x;
  const int row = tid >> 5, ks = tid & 31;
  const size_t m = (size_t)blockIdx.x * 16 + row;
  const float* hp = h1hist + m * 1024;
  float a[32];
  float s = 0.f, q = 0.f;
#pragma unroll
  for (int g = 0; g < 8; ++g) {
    const float4 v = *(const float4*)(hp + g * 128 + ks * 4);
    a[g*4+0] = v.x; a[g*4+1] = v.y; a[g*4+2] = v.z; a[g*4+3] = v.w;
    s += v.x + v.y + v.z + v.w;
    q += v.x * v.x + v.y * v.y + v.z * v.z + v.w * v.w;
  }
#pragma unroll
  for (int mk = 1; mk <= 16; mk <<= 1) { s += __shfl_xor(s, mk); q += __shfl_xor(q, mk); }
  const float mn = s * (1.f / 1024.f);
  const float rs = rsqrtf(q * (1.f / 1024.f) - mn * mn + 1e-5f);
#pragma unroll
  for (int g = 0; g < 8; ++g) {
    const float4 lw = *(const float4*)(ln1w + g * 128 + ks * 4);
    const float4 lb = *(const float4*)(ln1b + g * 128 + ks * 4);
    a[g*4+0] = (a[g*4+0] - mn) * rs * lw.x + lb.x;
    a[g*4+1] = (a[g*4+1] - mn) * rs * lw.y + lb.y;
    a[g*4+2] = (a[g*4+2] - mn) * rs * lw.z + lb.z;
    a[g*4+3] = (a[g*4+3] - mn) * rs * lw.w + lb.w;
  }
  for (int c = 0; c < 1024; ++c) {
    const float4* wp = (const float4*)(W1 + (size_t)c * 1024);
    float acc = 0.f;
#pragma unroll
    for (int g = 0; g < 8; ++g) {
      const float4 w = wp[g * 32 + ks];
      acc = fmaf(a[g*4+0], w.x, acc); acc = fmaf(a[g*4+1], w.y, acc);
      acc = fmaf(a[g*4+2], w.z, acc); acc = fmaf(a[g*4+3], w.w, acc);
    }
#pragma unroll
    for (int mk = 1; mk <= 16; mk <<= 1) acc += __shfl_xor(acc, mk);
    if (ks == 0) {
      const float y = acc + b1[c];
      araw[m * 1024 + c] = f2bf(y > 0.f ? y : 0.01f * y);
    }
  }
}

// ---------------- W2 -> bf16 (optional, ws-gated) ----------------
__global__ void k_w2q(const float* __restrict__ W2, short* __restrict__ W2q) {
  const int n = 32000 * 1024;
  for (int i = blockIdx.x * blockDim.x + threadIdx.x; i < n; i += gridDim.x * blockDim.x)
    W2q[i] = f2bf(W2[i]);
}

// ---------------- head GEMM (byte-identical to r15) ----------------
template <int BW2>
__global__ void k_head(const short* __restrict__ araw, const void* __restrict__ Bsrc,
                       const float* __restrict__ ln2w, const float* __restrict__ ln2b,
                       const float* __restrict__ b2, float* __restrict__ C) {
  __shared__ __align__(16) short As[128 * 64];
  __shared__ __align__(16) short Bs[128 * 64];
  __shared__ float rowm[128], rowr[128];
  __shared__ float lnw_s[1024], lnb_s[1024];
  __shared__ float ps[256], pq[256];
  const int tid = threadIdx.x;
  const long brow = (long)blockIdx.y * 128;
  const long bcol = (long)blockIdx.x * 128;

  for (int i = tid; i < 1024; i += 256) { lnw_s[i] = ln2w[i]; lnb_s[i] = ln2b[i]; }
  {
    const int r2 = tid >> 1, hf = tid & 1;
    const short* ap = araw + (brow + r2) * 1024 + hf * 512;
    float s = 0.f, q = 0.f;
    for (int j = 0; j < 512; j += 8) {
      const bf16x8 v = *(const bf16x8*)(ap + j);
#pragma unroll
      for (int e = 0; e < 8; ++e) { const float x = bf2f(v[e]); s += x; q += x * x; }
    }
    ps[tid] = s; pq[tid] = q;
  }
  __syncthreads();
  if (tid < 128) {
    const float s = ps[2 * tid] + ps[2 * tid + 1];
    const float q = pq[2 * tid] + pq[2 * tid + 1];
    const float m = s * (1.f / 1024.f);
    rowm[tid] = m;
    rowr[tid] = rsqrtf(q * (1.f / 1024.f) - m * m + 1e-5f);
  }
  __syncthreads();

  const int l = tid & 63;
  const int w = tid >> 6;
  const int wm = w >> 1, wn = w & 1;
  const int lane15 = l & 15, lgrp = l >> 4;
  f32x4 zero4 = {0.f, 0.f, 0.f, 0.f};
  f32x4 acc[4][4];
#pragma unroll
  for (int ri = 0; ri < 4; ++ri)
#pragma unroll
    for (int ci = 0; ci < 4; ++ci) acc[ri][ci] = zero4;

  for (int k0 = 0; k0 < 1024; k0 += 64) {
    __syncthreads();
#pragma unroll
    for (int i = 0; i < 4; ++i) {
      const int c = tid + i * 256;
      const int r = c >> 3, cc = c & 7;
      const int k = k0 + cc * 8;
      {
        const bf16x8 v = *(const bf16x8*)(araw + (brow + r) * 1024 + k);
        const float mm = rowm[r], rr = rowr[r];
        bf16x8 o;
#pragma unroll
        for (int e = 0; e < 8; ++e)
          o[e] = f2bf((bf2f(v[e]) - mm) * rr * lnw_s[k + e] + lnb_s[k + e]);
        *(bf16x8*)&As[r * 64 + cc * 8] = o;
      }
      if (BW2) {
        const short* bq = (const short*)Bsrc;
        *(bf16x8*)&Bs[r * 64 + cc * 8] = *(const bf16x8*)&bq[(bcol + r) * 1024 + k];
      } else {
        const float* bw = (const float*)Bsrc;
        const float4* bp = (const float4*)(bw + (bcol + r) * 1024 + k);
        const float4 v0 = bp[0], v1 = bp[1];
        bf16x8 o;
        o[0] = f2bf(v0.x); o[1] = f2bf(v0.y); o[2] = f2bf(v0.z); o[3] = f2bf(v0.w);
        o[4] = f2bf(v1.x); o[5] = f2bf(v1.y); o[6] = f2bf(v1.z); o[7] = f2bf(v1.w);
        *(bf16x8*)&Bs[r * 64 + cc * 8] = o;
      }
    }
    __syncthreads();
#pragma unroll
    for (int kk = 0; kk < 2; ++kk) {
      const int ko = kk * 32 + lgrp * 8;
      bf16x8 av[4], bv[4];
#pragma unroll
      for (int ri = 0; ri < 4; ++ri) av[ri] = *(const bf16x8*)&As[(wm * 64 + ri * 16 + lane15) * 64 + ko];
#pragma unroll
      for (int ci = 0; ci < 4; ++ci) bv[ci] = *(const bf16x8*)&Bs[(wn * 64 + ci * 16 + lane15) * 64 + ko];
#pragma unroll
      for (int ri = 0; ri < 4; ++ri)
#pragma unroll
        for (int ci = 0; ci < 4; ++ci) acc[ri][ci] = mfma16(av[ri], bv[ci], acc[ri][ci]);
    }
  }
#pragma unroll
  for (int ri = 0; ri < 4; ++ri)
#pragma unroll
    for (int ci = 0; ci < 4; ++ci)
#pragma unroll
      for (int i = 0; i < 4; ++i) {
        const long mrow = brow + wm * 64 + ri * 16 + lgrp * 4 + i;
        const long ncol = bcol + wn * 64 + ci * 16 + lane15;
        const int tq = (int)(mrow >> 4), b = (int)(mrow & 15);
        C[(size_t)b * TT * VOCAB + (size_t)tq * VOCAB + ncol] = acc[ri][ci][i] + b2[ncol];
      }
}

// ---------------- host launch ----------------
extern "C" void kernel_launch(void* const* d_in, const int* in_sizes, int n_in,
                              void* d_out, int out_size, void* d_ws, size_t ws_size,
                              hipStream_t stream) {
  const int* input = (const int*)d_in[0];
  const float* embd = (const float*)d_in[1];
  const float* Wih0 = (const float*)d_in[2];
  const float* Whh0 = (const float*)d_in[3];
  const float* bih0 = (const float*)d_in[4];
  const float* bhh0 = (const float*)d_in[5];
  const float* ln0w = (const float*)d_in[6];
  const float* ln0b = (const float*)d_in[7];
  const float* Wih1 = (const float*)d_in[8];
  const float* Whh1 = (const float*)d_in[9];
  const float* bih1 = (const float*)d_in[10];
  const float* bhh1 = (const float*)d_in[11];
  const float* ln1w = (const float*)d_in[12];
  const float* ln1b = (const float*)d_in[13];
  const float* W1 = (const float*)d_in[14];
  const float* b1 = (const float*)d_in[15];
  const float* ln2w = (const float*)d_in[16];
  const float* ln2b = (const float*)d_in[17];
  const float* W2 = (const float*)d_in[18];
  const float* b2 = (const float*)d_in[19];
  float* out = (float*)d_out;

  char* ws = (char*)d_ws;
  size_t off = 0;
  auto alloc = [&](size_t bytes) -> char* {
    char* p = ws + off;
    off = (off + bytes + 255) & ~(size_t)255;
    return p;
  };
  float* h1hist = (float*)alloc(4096ull * 1024 * 4);
  short* araw = (short*)alloc(4096ull * 1024 * 2);
  int* bar = (int*)alloc(16384);
  short* W2q = (short*)alloc(32000ull * 1024 * 2);
  const bool useW2q = (ws_size >= off);  // 88MB total; fall back if ws too small

  hipMemsetAsync(bar, 0, 16384, stream);

  // d_out as scratch (524 MB): gi0 (100.7 MB) + h0hist (33.5) + h1hist64 (33.5)
  // = 168 MB, all fully consumed before k_head overwrites every byte of d_out.
  char* od = (char*)d_out;
  double* gi0 = (double*)od;
  double* h0hist = (double*)(od + ((4096ull * 3072 * 8 + 255) & ~(size_t)255));
  double* h1hist64 = h0hist + (size_t)TT * 16 * 1024;

  k_gi0<<<4096, 256, 0, stream>>>(input, embd, Wih0, bih0, gi0);

  SP A;
  A.Whh0 = Whh0; A.bhh0 = bhh0; A.ln0w = ln0w; A.ln0b = ln0b;
  A.Wih1 = Wih1; A.Whh1 = Whh1; A.bih1 = bih1; A.bhh1 = bhh1;
  A.ln1w = ln1w; A.ln1b = ln1b;
  A.gi0 = gi0; A.h0hist = h0hist; A.h1hist64 = h1hist64; A.h1hist = h1hist;
  A.bar = bar;
  k_recur<<<NBLK, 512, 0, stream>>>(A);

  k_headpre<<<256, 512, 0, stream>>>(h1hist, ln1w, ln1b, W1, b1, araw);

  if (useW2q) {
    k_w2q<<<2048, 256, 0, stream>>>(W2, W2q);
    k_head<1><<<dim3(250, 32), 256, 0, stream>>>(araw, W2q, ln2w, ln2b, b2, out);
  } else {
    k_head<0><<<dim3(250, 32), 256, 0, stream>>>(araw, W2, ln2w, ln2b, b2, out);
  }
}